// Round 1
// baseline (7251.437 us; speedup 1.0000x reference)
//
#include <hip/hip_runtime.h>

#define D_FEAT 4096
#define HID 50
#define NC 6

// ---------------- GEMM1: H = relu(F @ W1 + b1) ----------------
// block: 256 threads = 16 col-groups (tx) x 16 row-groups (ty)
// block tile: 128 rows x 64 cols (cols padded 50->64 with zeros)
// per-thread tile: 8 rows x 4 cols; K staged in LDS chunks of 64 (W only)
#define G_ROWS 128
#define G_COLS 64
#define G_BK 64
#define G_TM 8

__global__ __launch_bounds__(256) void gemm1_relu(
    const float* __restrict__ F, const float* __restrict__ W1,
    const float* __restrict__ b1, float* __restrict__ H, int nrows)
{
    __shared__ float Ws[G_BK][G_COLS];  // 16 KB
    const int tid = threadIdx.x;
    const int tx = tid & 15;   // cols tx*4 .. tx*4+3
    const int ty = tid >> 4;   // rows ty*8 .. ty*8+7
    const long row0 = (long)blockIdx.x * G_ROWS;

    long roff[G_TM];
#pragma unroll
    for (int i = 0; i < G_TM; ++i) {
        long r = row0 + (long)ty * G_TM + i;
        if (r > (long)nrows - 1) r = (long)nrows - 1;  // clamp OOB loads
        roff[i] = r * (long)D_FEAT;
    }

    float acc[G_TM][4];
#pragma unroll
    for (int i = 0; i < G_TM; ++i)
#pragma unroll
        for (int j = 0; j < 4; ++j) acc[i][j] = 0.f;

    for (int k0 = 0; k0 < D_FEAT; k0 += G_BK) {
        __syncthreads();
        // stage W chunk: 64 k-rows x 64 cols (50 real, rest 0)
#pragma unroll
        for (int it = 0; it < (G_BK * G_COLS) / 256; ++it) {
            int i = tid + it * 256;
            int kk = i >> 6, c = i & 63;
            Ws[kk][c] = (c < HID) ? W1[(long)(k0 + kk) * HID + c] : 0.f;
        }
        __syncthreads();

#pragma unroll 2
        for (int k = 0; k < G_BK; k += 4) {
            float a[G_TM][4];
#pragma unroll
            for (int i = 0; i < G_TM; ++i) {
                const float4 t = *(const float4*)(F + roff[i] + k0 + k);
                a[i][0] = t.x; a[i][1] = t.y; a[i][2] = t.z; a[i][3] = t.w;
            }
            float w[4][4];
#pragma unroll
            for (int kk = 0; kk < 4; ++kk) {
                const float4 t = *(const float4*)&Ws[k + kk][tx * 4];
                w[kk][0] = t.x; w[kk][1] = t.y; w[kk][2] = t.z; w[kk][3] = t.w;
            }
#pragma unroll
            for (int kk = 0; kk < 4; ++kk)
#pragma unroll
                for (int i = 0; i < G_TM; ++i)
#pragma unroll
                    for (int j = 0; j < 4; ++j)
                        acc[i][j] = fmaf(a[i][kk], w[kk][j], acc[i][j]);
        }
    }

    // epilogue: bias + relu, store valid cols/rows
#pragma unroll
    for (int j = 0; j < 4; ++j) {
        int c = tx * 4 + j;
        if (c >= HID) continue;
        float bias = b1[c];
#pragma unroll
        for (int i = 0; i < G_TM; ++i) {
            long r = row0 + (long)ty * G_TM + i;
            if (r < nrows) {
                float v = acc[i][j] + bias;
                H[r * HID + c] = v > 0.f ? v : 0.f;
            }
        }
    }
}

// ---------------- MLP tail: x2=relu(H@W2+b2); x3=relu(x2@W3+b3); Z=x3@Wl+bl
__global__ __launch_bounds__(256) void mlp_tail(
    const float* __restrict__ H,
    const float* __restrict__ W2, const float* __restrict__ b2,
    const float* __restrict__ W3, const float* __restrict__ b3,
    const float* __restrict__ Wl, const float* __restrict__ bl,
    float* __restrict__ Z, int n)
{
    __shared__ float sW2[HID][52];
    __shared__ float sW3[HID][52];
    __shared__ float sWl[HID][8];
    __shared__ float sb2[HID], sb3[HID], sbl[8];

    for (int i = threadIdx.x; i < HID * 52; i += 256) {
        int r = i / 52, c = i % 52;
        sW2[r][c] = (c < HID) ? W2[r * HID + c] : 0.f;
        sW3[r][c] = (c < HID) ? W3[r * HID + c] : 0.f;
    }
    for (int i = threadIdx.x; i < HID * 8; i += 256) {
        int r = i / 8, c = i % 8;
        sWl[r][c] = (c < NC) ? Wl[r * NC + c] : 0.f;
    }
    if (threadIdx.x < HID) { sb2[threadIdx.x] = b2[threadIdx.x]; sb3[threadIdx.x] = b3[threadIdx.x]; }
    if (threadIdx.x < 8) sbl[threadIdx.x] = (threadIdx.x < NC) ? bl[threadIdx.x] : 0.f;
    __syncthreads();

    long row = (long)blockIdx.x * 256 + threadIdx.x;
    if (row >= n) return;

    float x1[HID];
#pragma unroll
    for (int i = 0; i < HID / 2; ++i) {
        float2 t = *(const float2*)(H + row * HID + 2 * i);
        x1[2 * i] = t.x; x1[2 * i + 1] = t.y;
    }

    float x2[52];
#pragma unroll
    for (int j = 0; j < HID; ++j) x2[j] = sb2[j];
    x2[50] = 0.f; x2[51] = 0.f;
    for (int i = 0; i < HID; ++i) {
        float xi = x1[i];
#pragma unroll
        for (int jq = 0; jq < 13; ++jq) {
            float4 t = *(const float4*)&sW2[i][jq * 4];
            x2[jq * 4 + 0] = fmaf(xi, t.x, x2[jq * 4 + 0]);
            x2[jq * 4 + 1] = fmaf(xi, t.y, x2[jq * 4 + 1]);
            x2[jq * 4 + 2] = fmaf(xi, t.z, x2[jq * 4 + 2]);
            x2[jq * 4 + 3] = fmaf(xi, t.w, x2[jq * 4 + 3]);
        }
    }

    float x3[52];
#pragma unroll
    for (int j = 0; j < HID; ++j) x3[j] = sb3[j];
    x3[50] = 0.f; x3[51] = 0.f;
    for (int i = 0; i < HID; ++i) {
        float xi = fmaxf(x2[i], 0.f);
#pragma unroll
        for (int jq = 0; jq < 13; ++jq) {
            float4 t = *(const float4*)&sW3[i][jq * 4];
            x3[jq * 4 + 0] = fmaf(xi, t.x, x3[jq * 4 + 0]);
            x3[jq * 4 + 1] = fmaf(xi, t.y, x3[jq * 4 + 1]);
            x3[jq * 4 + 2] = fmaf(xi, t.z, x3[jq * 4 + 2]);
            x3[jq * 4 + 3] = fmaf(xi, t.w, x3[jq * 4 + 3]);
        }
    }

    float z[NC];
#pragma unroll
    for (int c = 0; c < NC; ++c) z[c] = sbl[c];
    for (int i = 0; i < HID; ++i) {
        float xi = fmaxf(x3[i], 0.f);
#pragma unroll
        for (int c = 0; c < NC; ++c) z[c] = fmaf(xi, sWl[i][c], z[c]);
    }
#pragma unroll
    for (int c = 0; c < NC; ++c) Z[row * NC + c] = z[c];
}

// ---------------- KENN edge layer: Znew (pre-initialized to Zold) += deltas
__global__ __launch_bounds__(256) void kenn_edge(
    const float* __restrict__ Zold, float* __restrict__ Znew,
    const float* __restrict__ rel, const int* __restrict__ sx,
    const int* __restrict__ sy, const float* __restrict__ cw, int m)
{
    int idx = blockIdx.x * 256 + threadIdx.x;
    if (idx >= m) return;
    const int x = sx[idx];
    const int y = sy[idx];
    const float l0 = -rel[idx];

    float zx[NC], zy[NC];
    const float2* px = (const float2*)(Zold + 6L * x);
    const float2* py = (const float2*)(Zold + 6L * y);
#pragma unroll
    for (int q = 0; q < 3; ++q) {
        float2 t = px[q]; zx[2 * q] = t.x; zx[2 * q + 1] = t.y;
        float2 u = py[q]; zy[2 * q] = u.x; zy[2 * q + 1] = u.y;
    }

#pragma unroll
    for (int c = 0; c < NC; ++c) {
        float l1 = -zx[c];
        float l2 = zy[c];
        float mx = fmaxf(l0, fmaxf(l1, l2));
        float e0 = __expf(l0 - mx);
        float e1 = __expf(l1 - mx);
        float e2 = __expf(l2 - mx);
        float s = cw[c] / (e0 + e1 + e2);
        atomicAdd(&Znew[6L * x + c], -e1 * s);
        atomicAdd(&Znew[6L * y + c],  e2 * s);
    }
}

// ---------------- final row softmax over 6 classes ----------------
__global__ __launch_bounds__(256) void softmax6(
    const float* __restrict__ Z, float* __restrict__ out, int n)
{
    long row = (long)blockIdx.x * 256 + threadIdx.x;
    if (row >= n) return;
    float v[NC];
    const float2* p = (const float2*)(Z + row * 6);
#pragma unroll
    for (int q = 0; q < 3; ++q) { float2 t = p[q]; v[2 * q] = t.x; v[2 * q + 1] = t.y; }
    float mx = v[0];
#pragma unroll
    for (int c = 1; c < NC; ++c) mx = fmaxf(mx, v[c]);
    float e[NC], s = 0.f;
#pragma unroll
    for (int c = 0; c < NC; ++c) { e[c] = __expf(v[c] - mx); s += e[c]; }
    float inv = 1.f / s;
    float2* po = (float2*)(out + row * 6);
#pragma unroll
    for (int q = 0; q < 3; ++q) {
        float2 t; t.x = e[2 * q] * inv; t.y = e[2 * q + 1] * inv;
        po[q] = t;
    }
}

extern "C" void kernel_launch(void* const* d_in, const int* in_sizes, int n_in,
                              void* d_out, int out_size, void* d_ws, size_t ws_size,
                              hipStream_t stream)
{
    const float* F   = (const float*)d_in[0];
    const float* rel = (const float*)d_in[1];
    const int*   sx  = (const int*)d_in[2];
    const int*   sy  = (const int*)d_in[3];
    const float* W1  = (const float*)d_in[4];
    const float* b1  = (const float*)d_in[5];
    const float* W2  = (const float*)d_in[6];
    const float* b2  = (const float*)d_in[7];
    const float* W3  = (const float*)d_in[8];
    const float* b3  = (const float*)d_in[9];
    const float* Wl  = (const float*)d_in[10];
    const float* bl  = (const float*)d_in[11];
    const float* cw1 = (const float*)d_in[12];
    const float* cw2 = (const float*)d_in[13];
    const float* cw3 = (const float*)d_in[14];

    const int n = in_sizes[0] / D_FEAT;   // 100000
    const int m = in_sizes[1];            // 3200000

    float* H  = (float*)d_ws;                      // n*50 floats (20 MB)
    float* Z0 = H + (size_t)n * HID;               // n*6 floats
    float* Z1 = Z0 + (size_t)n * NC;               // n*6 floats

    gemm1_relu<<<(n + G_ROWS - 1) / G_ROWS, 256, 0, stream>>>(F, W1, b1, H, n);
    mlp_tail<<<(n + 255) / 256, 256, 0, stream>>>(H, W2, b2, W3, b3, Wl, bl, Z0, n);

    const size_t zbytes = (size_t)n * NC * sizeof(float);
    const int eblocks = (m + 255) / 256;

    hipMemcpyAsync(Z1, Z0, zbytes, hipMemcpyDeviceToDevice, stream);
    kenn_edge<<<eblocks, 256, 0, stream>>>(Z0, Z1, rel, sx, sy, cw1, m);
    hipMemcpyAsync(Z0, Z1, zbytes, hipMemcpyDeviceToDevice, stream);
    kenn_edge<<<eblocks, 256, 0, stream>>>(Z1, Z0, rel, sx, sy, cw2, m);
    hipMemcpyAsync(Z1, Z0, zbytes, hipMemcpyDeviceToDevice, stream);
    kenn_edge<<<eblocks, 256, 0, stream>>>(Z0, Z1, rel, sx, sy, cw3, m);

    softmax6<<<(n + 255) / 256, 256, 0, stream>>>(Z1, (float*)d_out, n);
}

// Round 2
// 2719.278 us; speedup vs baseline: 2.6667x; 2.6667x over previous
//
#include <hip/hip_runtime.h>

#define D_FEAT 4096
#define HID 50
#define NC 6

// ---------------- GEMM1: H = relu(F @ W1 + b1) ----------------
#define G_ROWS 128
#define G_COLS 64
#define G_BK 64
#define G_TM 8

__global__ __launch_bounds__(256) void gemm1_relu(
    const float* __restrict__ F, const float* __restrict__ W1,
    const float* __restrict__ b1, float* __restrict__ H, int nrows)
{
    __shared__ float Ws[G_BK][G_COLS];  // 16 KB
    const int tid = threadIdx.x;
    const int tx = tid & 15;
    const int ty = tid >> 4;
    const long row0 = (long)blockIdx.x * G_ROWS;

    long roff[G_TM];
#pragma unroll
    for (int i = 0; i < G_TM; ++i) {
        long r = row0 + (long)ty * G_TM + i;
        if (r > (long)nrows - 1) r = (long)nrows - 1;
        roff[i] = r * (long)D_FEAT;
    }

    float acc[G_TM][4];
#pragma unroll
    for (int i = 0; i < G_TM; ++i)
#pragma unroll
        for (int j = 0; j < 4; ++j) acc[i][j] = 0.f;

    for (int k0 = 0; k0 < D_FEAT; k0 += G_BK) {
        __syncthreads();
#pragma unroll
        for (int it = 0; it < (G_BK * G_COLS) / 256; ++it) {
            int i = tid + it * 256;
            int kk = i >> 6, c = i & 63;
            Ws[kk][c] = (c < HID) ? W1[(long)(k0 + kk) * HID + c] : 0.f;
        }
        __syncthreads();

#pragma unroll 2
        for (int k = 0; k < G_BK; k += 4) {
            float a[G_TM][4];
#pragma unroll
            for (int i = 0; i < G_TM; ++i) {
                const float4 t = *(const float4*)(F + roff[i] + k0 + k);
                a[i][0] = t.x; a[i][1] = t.y; a[i][2] = t.z; a[i][3] = t.w;
            }
            float w[4][4];
#pragma unroll
            for (int kk = 0; kk < 4; ++kk) {
                const float4 t = *(const float4*)&Ws[k + kk][tx * 4];
                w[kk][0] = t.x; w[kk][1] = t.y; w[kk][2] = t.z; w[kk][3] = t.w;
            }
#pragma unroll
            for (int kk = 0; kk < 4; ++kk)
#pragma unroll
                for (int i = 0; i < G_TM; ++i)
#pragma unroll
                    for (int j = 0; j < 4; ++j)
                        acc[i][j] = fmaf(a[i][kk], w[kk][j], acc[i][j]);
        }
    }

#pragma unroll
    for (int j = 0; j < 4; ++j) {
        int c = tx * 4 + j;
        if (c >= HID) continue;
        float bias = b1[c];
#pragma unroll
        for (int i = 0; i < G_TM; ++i) {
            long r = row0 + (long)ty * G_TM + i;
            if (r < nrows) {
                float v = acc[i][j] + bias;
                H[r * HID + c] = v > 0.f ? v : 0.f;
            }
        }
    }
}

// ---------------- MLP tail ----------------
__global__ __launch_bounds__(256) void mlp_tail(
    const float* __restrict__ H,
    const float* __restrict__ W2, const float* __restrict__ b2,
    const float* __restrict__ W3, const float* __restrict__ b3,
    const float* __restrict__ Wl, const float* __restrict__ bl,
    float* __restrict__ Z, int n)
{
    __shared__ float sW2[HID][52];
    __shared__ float sW3[HID][52];
    __shared__ float sWl[HID][8];
    __shared__ float sb2[HID], sb3[HID], sbl[8];

    for (int i = threadIdx.x; i < HID * 52; i += 256) {
        int r = i / 52, c = i % 52;
        sW2[r][c] = (c < HID) ? W2[r * HID + c] : 0.f;
        sW3[r][c] = (c < HID) ? W3[r * HID + c] : 0.f;
    }
    for (int i = threadIdx.x; i < HID * 8; i += 256) {
        int r = i / 8, c = i % 8;
        sWl[r][c] = (c < NC) ? Wl[r * NC + c] : 0.f;
    }
    if (threadIdx.x < HID) { sb2[threadIdx.x] = b2[threadIdx.x]; sb3[threadIdx.x] = b3[threadIdx.x]; }
    if (threadIdx.x < 8) sbl[threadIdx.x] = (threadIdx.x < NC) ? bl[threadIdx.x] : 0.f;
    __syncthreads();

    long row = (long)blockIdx.x * 256 + threadIdx.x;
    if (row >= n) return;

    float x1[HID];
#pragma unroll
    for (int i = 0; i < HID / 2; ++i) {
        float2 t = *(const float2*)(H + row * HID + 2 * i);
        x1[2 * i] = t.x; x1[2 * i + 1] = t.y;
    }

    float x2[52];
#pragma unroll
    for (int j = 0; j < HID; ++j) x2[j] = sb2[j];
    x2[50] = 0.f; x2[51] = 0.f;
    for (int i = 0; i < HID; ++i) {
        float xi = x1[i];
#pragma unroll
        for (int jq = 0; jq < 13; ++jq) {
            float4 t = *(const float4*)&sW2[i][jq * 4];
            x2[jq * 4 + 0] = fmaf(xi, t.x, x2[jq * 4 + 0]);
            x2[jq * 4 + 1] = fmaf(xi, t.y, x2[jq * 4 + 1]);
            x2[jq * 4 + 2] = fmaf(xi, t.z, x2[jq * 4 + 2]);
            x2[jq * 4 + 3] = fmaf(xi, t.w, x2[jq * 4 + 3]);
        }
    }

    float x3[52];
#pragma unroll
    for (int j = 0; j < HID; ++j) x3[j] = sb3[j];
    x3[50] = 0.f; x3[51] = 0.f;
    for (int i = 0; i < HID; ++i) {
        float xi = fmaxf(x2[i], 0.f);
#pragma unroll
        for (int jq = 0; jq < 13; ++jq) {
            float4 t = *(const float4*)&sW3[i][jq * 4];
            x3[jq * 4 + 0] = fmaf(xi, t.x, x3[jq * 4 + 0]);
            x3[jq * 4 + 1] = fmaf(xi, t.y, x3[jq * 4 + 1]);
            x3[jq * 4 + 2] = fmaf(xi, t.z, x3[jq * 4 + 2]);
            x3[jq * 4 + 3] = fmaf(xi, t.w, x3[jq * 4 + 3]);
        }
    }

    float z[NC];
#pragma unroll
    for (int c = 0; c < NC; ++c) z[c] = sbl[c];
    for (int i = 0; i < HID; ++i) {
        float xi = fmaxf(x3[i], 0.f);
#pragma unroll
        for (int c = 0; c < NC; ++c) z[c] = fmaf(xi, sWl[i][c], z[c]);
    }
#pragma unroll
    for (int c = 0; c < NC; ++c) Z[row * NC + c] = z[c];
}

// ================= CSR binning (once per call) =================
__global__ __launch_bounds__(256) void count_deg(
    const int* __restrict__ sx, const int* __restrict__ sy,
    int* __restrict__ deg, int m)
{
    int e = blockIdx.x * 256 + threadIdx.x;
    if (e >= m) return;
    atomicAdd(&deg[sx[e]], 1);
    atomicAdd(&deg[sy[e]], 1);
}

__global__ __launch_bounds__(256) void scan1(
    const int* __restrict__ deg, int* __restrict__ offs,
    int* __restrict__ bsum, int n)
{
    __shared__ int s[256];
    int t = threadIdx.x;
    int i = blockIdx.x * 256 + t;
    int v = (i < n) ? deg[i] : 0;
    s[t] = v;
    __syncthreads();
    for (int st = 1; st < 256; st <<= 1) {
        int tmp = (t >= st) ? s[t - st] : 0;
        __syncthreads();
        s[t] += tmp;
        __syncthreads();
    }
    if (i < n) offs[i] = s[t] - v;      // block-local exclusive
    if (t == 255) bsum[blockIdx.x] = s[255];
}

__global__ __launch_bounds__(1024) void scan2(
    int* __restrict__ bsum, int* __restrict__ bbase, int nb)
{
    __shared__ int s[1024];
    int t = threadIdx.x;
    int v = (t < nb) ? bsum[t] : 0;
    s[t] = v;
    __syncthreads();
    for (int st = 1; st < 1024; st <<= 1) {
        int tmp = (t >= st) ? s[t - st] : 0;
        __syncthreads();
        s[t] += tmp;
        __syncthreads();
    }
    if (t < nb) bbase[t] = s[t] - v;    // exclusive over block sums
}

__global__ __launch_bounds__(256) void scan3(
    int* __restrict__ offs, const int* __restrict__ bbase,
    int* __restrict__ cur, int n)
{
    int i = blockIdx.x * 256 + threadIdx.x;
    if (i >= n) return;
    int o = offs[i] + bbase[blockIdx.x];
    offs[i] = o;
    cur[i] = o;
}

// record: .x = other_node | (side<<31)  (side 0: own is sx / x-copy, 1: own is sy)
//         .y = rel bits
__global__ __launch_bounds__(256) void scatter_recs(
    const int* __restrict__ sx, const int* __restrict__ sy,
    const float* __restrict__ rel, int* __restrict__ cur,
    uint2* __restrict__ recs, int m)
{
    int e = blockIdx.x * 256 + threadIdx.x;
    if (e >= m) return;
    int x = sx[e], y = sy[e];
    unsigned rb = __float_as_uint(rel[e]);
    int px = atomicAdd(&cur[x], 1);
    recs[px] = make_uint2((unsigned)y, rb);
    int py = atomicAdd(&cur[y], 1);
    recs[py] = make_uint2((unsigned)x | 0x80000000u, rb);
}

// ============ KENN layer as pure gather (no atomics) ============
__global__ __launch_bounds__(256) void kenn_gather(
    const float* __restrict__ Zin, float* __restrict__ Zout,
    const int* __restrict__ offs, const int* __restrict__ deg,
    const uint2* __restrict__ recs, const float* __restrict__ cw,
    int n, int dofinal)
{
    int node = blockIdx.x * 256 + threadIdx.x;
    if (node >= n) return;

    float zown[NC], acc[NC], cwv[NC];
    const float2* pz = (const float2*)(Zin + 6L * node);
#pragma unroll
    for (int q = 0; q < 3; ++q) {
        float2 t = pz[q];
        zown[2 * q] = t.x; zown[2 * q + 1] = t.y;
    }
#pragma unroll
    for (int c = 0; c < NC; ++c) { acc[c] = zown[c]; cwv[c] = cw[c]; }

    const int start = offs[node];
    const int cnt = deg[node];

    for (int i = 0; i < cnt; ++i) {
        uint2 rc = recs[start + i];
        const int other = (int)(rc.x & 0x7FFFFFFFu);
        const bool sideY = (rc.x & 0x80000000u) != 0;  // own is y-copy
        const float l0 = -__uint_as_float(rc.y);

        float zo[NC];
        const float2* po = (const float2*)(Zin + 6L * other);
#pragma unroll
        for (int q = 0; q < 3; ++q) {
            float2 t = po[q];
            zo[2 * q] = t.x; zo[2 * q + 1] = t.y;
        }

#pragma unroll
        for (int c = 0; c < NC; ++c) {
            float zx = sideY ? zo[c] : zown[c];
            float zy = sideY ? zown[c] : zo[c];
            float l1 = -zx;
            float l2 = zy;
            float mx = fmaxf(l0, fmaxf(l1, l2));
            float e0 = __expf(l0 - mx);
            float e1 = __expf(l1 - mx);
            float e2 = __expf(l2 - mx);
            float g = cwv[c] / (e0 + e1 + e2);
            acc[c] += sideY ? (e2 * g) : (-e1 * g);
        }
    }

    if (dofinal) {
        float mx = acc[0];
#pragma unroll
        for (int c = 1; c < NC; ++c) mx = fmaxf(mx, acc[c]);
        float e[NC], s = 0.f;
#pragma unroll
        for (int c = 0; c < NC; ++c) { e[c] = __expf(acc[c] - mx); s += e[c]; }
        float inv = 1.f / s;
        float2* po = (float2*)(Zout + 6L * node);
#pragma unroll
        for (int q = 0; q < 3; ++q) {
            float2 t; t.x = e[2 * q] * inv; t.y = e[2 * q + 1] * inv;
            po[q] = t;
        }
    } else {
        float2* po = (float2*)(Zout + 6L * node);
#pragma unroll
        for (int q = 0; q < 3; ++q) {
            float2 t; t.x = acc[2 * q]; t.y = acc[2 * q + 1];
            po[q] = t;
        }
    }
}

// ---------------- fallback path kernels (old atomic version) ----------------
__global__ __launch_bounds__(256) void kenn_edge(
    const float* __restrict__ Zold, float* __restrict__ Znew,
    const float* __restrict__ rel, const int* __restrict__ sx,
    const int* __restrict__ sy, const float* __restrict__ cw, int m)
{
    int idx = blockIdx.x * 256 + threadIdx.x;
    if (idx >= m) return;
    const int x = sx[idx];
    const int y = sy[idx];
    const float l0 = -rel[idx];

    float zx[NC], zy[NC];
    const float2* px = (const float2*)(Zold + 6L * x);
    const float2* py = (const float2*)(Zold + 6L * y);
#pragma unroll
    for (int q = 0; q < 3; ++q) {
        float2 t = px[q]; zx[2 * q] = t.x; zx[2 * q + 1] = t.y;
        float2 u = py[q]; zy[2 * q] = u.x; zy[2 * q + 1] = u.y;
    }
#pragma unroll
    for (int c = 0; c < NC; ++c) {
        float l1 = -zx[c];
        float l2 = zy[c];
        float mx = fmaxf(l0, fmaxf(l1, l2));
        float e0 = __expf(l0 - mx);
        float e1 = __expf(l1 - mx);
        float e2 = __expf(l2 - mx);
        float s = cw[c] / (e0 + e1 + e2);
        atomicAdd(&Znew[6L * x + c], -e1 * s);
        atomicAdd(&Znew[6L * y + c],  e2 * s);
    }
}

__global__ __launch_bounds__(256) void softmax6(
    const float* __restrict__ Z, float* __restrict__ out, int n)
{
    long row = (long)blockIdx.x * 256 + threadIdx.x;
    if (row >= n) return;
    float v[NC];
    const float2* p = (const float2*)(Z + row * 6);
#pragma unroll
    for (int q = 0; q < 3; ++q) { float2 t = p[q]; v[2 * q] = t.x; v[2 * q + 1] = t.y; }
    float mx = v[0];
#pragma unroll
    for (int c = 1; c < NC; ++c) mx = fmaxf(mx, v[c]);
    float e[NC], s = 0.f;
#pragma unroll
    for (int c = 0; c < NC; ++c) { e[c] = __expf(v[c] - mx); s += e[c]; }
    float inv = 1.f / s;
    float2* po = (float2*)(out + row * 6);
#pragma unroll
    for (int q = 0; q < 3; ++q) {
        float2 t; t.x = e[2 * q] * inv; t.y = e[2 * q + 1] * inv;
        po[q] = t;
    }
}

extern "C" void kernel_launch(void* const* d_in, const int* in_sizes, int n_in,
                              void* d_out, int out_size, void* d_ws, size_t ws_size,
                              hipStream_t stream)
{
    const float* F   = (const float*)d_in[0];
    const float* rel = (const float*)d_in[1];
    const int*   sx  = (const int*)d_in[2];
    const int*   sy  = (const int*)d_in[3];
    const float* W1  = (const float*)d_in[4];
    const float* b1  = (const float*)d_in[5];
    const float* W2  = (const float*)d_in[6];
    const float* b2  = (const float*)d_in[7];
    const float* W3  = (const float*)d_in[8];
    const float* b3  = (const float*)d_in[9];
    const float* Wl  = (const float*)d_in[10];
    const float* bl  = (const float*)d_in[11];
    const float* cw1 = (const float*)d_in[12];
    const float* cw2 = (const float*)d_in[13];
    const float* cw3 = (const float*)d_in[14];

    const int n = in_sizes[0] / D_FEAT;   // 100000
    const int m = in_sizes[1];            // 3200000

    // workspace layout
    float* H  = (float*)d_ws;                       // n*HID
    float* Z0 = H + (size_t)n * HID;                // n*6
    float* Z1 = Z0 + (size_t)n * NC;                // n*6
    int* deg  = (int*)(Z1 + (size_t)n * NC);        // n
    int* offs = deg + n;                            // n
    int* cur  = offs + n;                           // n
    int* bsum = cur + n;                            // 1024
    int* bbase = bsum + 1024;                       // 1024
    uint2* recs = (uint2*)(bbase + 1024);           // 2m  (8B-aligned: even float count)

    const size_t need = ((char*)(recs + 2 * (size_t)m)) - (char*)d_ws;

    gemm1_relu<<<(n + G_ROWS - 1) / G_ROWS, 256, 0, stream>>>(F, W1, b1, H, n);
    mlp_tail<<<(n + 255) / 256, 256, 0, stream>>>(H, W2, b2, W3, b3, Wl, bl, Z0, n);

    const int nblk = (n + 255) / 256;
    const int eblk = (m + 255) / 256;

    if (ws_size >= need) {
        // --- build CSR incidence list ---
        hipMemsetAsync(deg, 0, (size_t)n * sizeof(int), stream);
        count_deg<<<eblk, 256, 0, stream>>>(sx, sy, deg, m);
        scan1<<<nblk, 256, 0, stream>>>(deg, offs, bsum, n);
        scan2<<<1, 1024, 0, stream>>>(bsum, bbase, nblk);
        scan3<<<nblk, 256, 0, stream>>>(offs, bbase, cur, n);
        scatter_recs<<<eblk, 256, 0, stream>>>(sx, sy, rel, cur, recs, m);

        // --- 3 KENN layers as pure gathers; last fuses final softmax ---
        kenn_gather<<<nblk, 256, 0, stream>>>(Z0, Z1, offs, deg, recs, cw1, n, 0);
        kenn_gather<<<nblk, 256, 0, stream>>>(Z1, Z0, offs, deg, recs, cw2, n, 0);
        kenn_gather<<<nblk, 256, 0, stream>>>(Z0, (float*)d_out, offs, deg, recs, cw3, n, 1);
    } else {
        // fallback: old atomic-scatter path (needs only H+Z0+Z1)
        const size_t zbytes = (size_t)n * NC * sizeof(float);
        hipMemcpyAsync(Z1, Z0, zbytes, hipMemcpyDeviceToDevice, stream);
        kenn_edge<<<eblk, 256, 0, stream>>>(Z0, Z1, rel, sx, sy, cw1, m);
        hipMemcpyAsync(Z0, Z1, zbytes, hipMemcpyDeviceToDevice, stream);
        kenn_edge<<<eblk, 256, 0, stream>>>(Z1, Z0, rel, sx, sy, cw2, m);
        hipMemcpyAsync(Z1, Z0, zbytes, hipMemcpyDeviceToDevice, stream);
        kenn_edge<<<eblk, 256, 0, stream>>>(Z0, Z1, rel, sx, sy, cw3, m);
        softmax6<<<nblk, 256, 0, stream>>>(Z1, (float*)d_out, n);
    }
}

// Round 3
// 1774.502 us; speedup vs baseline: 4.0865x; 1.5324x over previous
//
#include <hip/hip_runtime.h>

#define D_FEAT 4096
#define HID 50
#define NC 6

typedef __attribute__((ext_vector_type(8))) short bf16x8;
typedef __attribute__((ext_vector_type(4))) float f32x4;

// ============ W1 -> bf16 hi/lo MFMA B-fragment pre-pack ============
// frag idx: ((kc*4 + ct)*64 + l)*8 + j  ->  k = kc*32 + (l>>4)*8 + j,
//                                           c = ct*16 + (l&15)  (c>=50 -> 0)
__global__ __launch_bounds__(256) void prep_wfrag(
    const float* __restrict__ W1, ushort* __restrict__ Whi,
    ushort* __restrict__ Wlo)
{
    int idx = blockIdx.x * 256 + threadIdx.x;   // 0 .. 128*4*64*8-1
    int j  = idx & 7;
    int l  = (idx >> 3) & 63;
    int ct = (idx >> 9) & 3;
    int kc = idx >> 11;
    int k = kc * 32 + (l >> 4) * 8 + j;
    int c = ct * 16 + (l & 15);
    float v = (c < HID) ? W1[k * HID + c] : 0.f;
    unsigned b = __float_as_uint(v);
    unsigned h = (b + 0x8000u) >> 16;                 // round-half-up bf16
    float hf = __uint_as_float(h << 16);
    float lr = v - hf;
    unsigned lo = (__float_as_uint(lr) + 0x8000u) >> 16;
    Whi[idx] = (ushort)h;
    Wlo[idx] = (ushort)lo;
}

// ============ GEMM1 via MFMA bf16x3: H = relu(F @ W1 + b1) ============
// block = 256 thr = 4 waves; block tile 128 rows x 64 cols;
// wave tile 32 rows (2 mfma row-tiles) x 64 cols (4 col-tiles); K chunk 32.
__global__ __launch_bounds__(256) void gemm1_mfma(
    const float* __restrict__ F, const ushort* __restrict__ Whi,
    const ushort* __restrict__ Wlo, const float* __restrict__ b1,
    float* __restrict__ H, int nrows)
{
    const int tid = threadIdx.x;
    const int w  = tid >> 6;
    const int l  = tid & 63;
    const int l16 = l & 15, lq = l >> 4;
    const long rowb = (long)blockIdx.x * 128 + (long)w * 32;

    const float* fp[2];
#pragma unroll
    for (int rt = 0; rt < 2; ++rt) {
        long r = rowb + rt * 16 + l16;
        if (r > (long)nrows - 1) r = (long)nrows - 1;
        fp[rt] = F + r * (long)D_FEAT + lq * 8;
    }
    const bf16x8* bhip = (const bf16x8*)Whi + l;   // + kc*256 + ct*64
    const bf16x8* blop = (const bf16x8*)Wlo + l;

    f32x4 acc[2][4];
#pragma unroll
    for (int rt = 0; rt < 2; ++rt)
#pragma unroll
        for (int ct = 0; ct < 4; ++ct)
#pragma unroll
            for (int i = 0; i < 4; ++i) acc[rt][ct][i] = 0.f;

    // register double-buffer: preload chunk 0
    f32x4 an[2][2];
    bf16x8 bhn[4], bln[4];
#pragma unroll
    for (int rt = 0; rt < 2; ++rt) {
        an[rt][0] = *(const f32x4*)(fp[rt]);
        an[rt][1] = *(const f32x4*)(fp[rt] + 4);
    }
#pragma unroll
    for (int ct = 0; ct < 4; ++ct) { bhn[ct] = bhip[ct * 64]; bln[ct] = blop[ct * 64]; }

    for (int kc = 0; kc < 128; ++kc) {
        f32x4 ac[2][2];
        bf16x8 bh[4], bl[4];
#pragma unroll
        for (int rt = 0; rt < 2; ++rt) { ac[rt][0] = an[rt][0]; ac[rt][1] = an[rt][1]; }
#pragma unroll
        for (int ct = 0; ct < 4; ++ct) { bh[ct] = bhn[ct]; bl[ct] = bln[ct]; }

        if (kc < 127) {
            const int kn = kc + 1;
#pragma unroll
            for (int rt = 0; rt < 2; ++rt) {
                an[rt][0] = *(const f32x4*)(fp[rt] + kn * 32);
                an[rt][1] = *(const f32x4*)(fp[rt] + kn * 32 + 4);
            }
#pragma unroll
            for (int ct = 0; ct < 4; ++ct) {
                bhn[ct] = bhip[kn * 256 + ct * 64];
                bln[ct] = blop[kn * 256 + ct * 64];
            }
        }

        // split A fp32 -> bf16 hi/lo in-register
        bf16x8 ahi[2], alo[2];
#pragma unroll
        for (int rt = 0; rt < 2; ++rt) {
#pragma unroll
            for (int j = 0; j < 8; ++j) {
                float v = (j < 4) ? ac[rt][0][j] : ac[rt][1][j - 4];
                unsigned b = __float_as_uint(v);
                unsigned h = (b + 0x8000u) >> 16;
                float hf = __uint_as_float(h << 16);
                float lr = v - hf;
                unsigned lo = (__float_as_uint(lr) + 0x8000u) >> 16;
                ahi[rt][j] = (short)h;
                alo[rt][j] = (short)lo;
            }
        }

#pragma unroll
        for (int rt = 0; rt < 2; ++rt)
#pragma unroll
            for (int ct = 0; ct < 4; ++ct) {
                acc[rt][ct] = __builtin_amdgcn_mfma_f32_16x16x32_bf16(ahi[rt], bh[ct], acc[rt][ct], 0, 0, 0);
                acc[rt][ct] = __builtin_amdgcn_mfma_f32_16x16x32_bf16(ahi[rt], bl[ct], acc[rt][ct], 0, 0, 0);
                acc[rt][ct] = __builtin_amdgcn_mfma_f32_16x16x32_bf16(alo[rt], bh[ct], acc[rt][ct], 0, 0, 0);
            }
    }

    // epilogue: D row = (lane>>4)*4 + i, col = ct*16 + (lane&15)
#pragma unroll
    for (int ct = 0; ct < 4; ++ct) {
        int col = ct * 16 + l16;
        if (col >= HID) continue;
        float bias = b1[col];
#pragma unroll
        for (int rt = 0; rt < 2; ++rt)
#pragma unroll
            for (int i = 0; i < 4; ++i) {
                long row = rowb + rt * 16 + lq * 4 + i;
                if (row < nrows) {
                    float v = acc[rt][ct][i] + bias;
                    H[row * HID + col] = v > 0.f ? v : 0.f;
                }
            }
    }
}

// ---------------- MLP tail (register-lean, no x3 array) ----------------
__global__ __launch_bounds__(256) void mlp_tail(
    const float* __restrict__ H,
    const float* __restrict__ W2, const float* __restrict__ b2,
    const float* __restrict__ W3, const float* __restrict__ b3,
    const float* __restrict__ Wl, const float* __restrict__ bl,
    float* __restrict__ Z, int n)
{
    __shared__ float sW2[HID][52];
    __shared__ float sW3[HID][52];
    __shared__ float sWl[52][8];
    __shared__ float sb2[52], sb3[52], sbl[8];

    for (int i = threadIdx.x; i < HID * 52; i += 256) {
        int r = i / 52, c = i % 52;
        sW2[r][c] = (c < HID) ? W2[r * HID + c] : 0.f;
        sW3[r][c] = (c < HID) ? W3[r * HID + c] : 0.f;
    }
    for (int i = threadIdx.x; i < 52 * 8; i += 256) {
        int r = i / 8, c = i % 8;
        sWl[r][c] = (r < HID && c < NC) ? Wl[r * NC + c] : 0.f;
    }
    if (threadIdx.x < 52) {
        sb2[threadIdx.x] = (threadIdx.x < HID) ? b2[threadIdx.x] : 0.f;
        sb3[threadIdx.x] = (threadIdx.x < HID) ? b3[threadIdx.x] : 0.f;
    }
    if (threadIdx.x < 8) sbl[threadIdx.x] = (threadIdx.x < NC) ? bl[threadIdx.x] : 0.f;
    __syncthreads();

    long row = (long)blockIdx.x * 256 + threadIdx.x;
    if (row >= n) return;

    // phase 0: load H row (already relu'd)
    float x1[HID];
#pragma unroll
    for (int i = 0; i < HID / 2; ++i) {
        float2 t = *(const float2*)(H + row * HID + 2 * i);
        x1[2 * i] = t.x; x1[2 * i + 1] = t.y;
    }

    // phase 1: x2 = relu(x1 @ W2 + b2)  (store relu'd)
    float x2[52];
#pragma unroll
    for (int j = 0; j < 52; ++j) x2[j] = sb2[j];
    for (int i = 0; i < HID; ++i) {
        float xi = x1[i];
#pragma unroll
        for (int jq = 0; jq < 13; ++jq) {
            float4 t = *(const float4*)&sW2[i][jq * 4];
            x2[jq * 4 + 0] = fmaf(xi, t.x, x2[jq * 4 + 0]);
            x2[jq * 4 + 1] = fmaf(xi, t.y, x2[jq * 4 + 1]);
            x2[jq * 4 + 2] = fmaf(xi, t.z, x2[jq * 4 + 2]);
            x2[jq * 4 + 3] = fmaf(xi, t.w, x2[jq * 4 + 3]);
        }
    }
#pragma unroll
    for (int j = 0; j < 52; ++j) x2[j] = fmaxf(x2[j], 0.f);

    // phase 2: x3 in chunks of 4, folded into z immediately
    float z[NC];
#pragma unroll
    for (int c = 0; c < NC; ++c) z[c] = sbl[c];
    for (int jq = 0; jq < 13; ++jq) {
        float t0 = sb3[jq * 4 + 0], t1 = sb3[jq * 4 + 1];
        float t2 = sb3[jq * 4 + 2], t3 = sb3[jq * 4 + 3];
        for (int k = 0; k < HID; ++k) {
            float xk = x2[k];
            float4 wv = *(const float4*)&sW3[k][jq * 4];
            t0 = fmaf(xk, wv.x, t0);
            t1 = fmaf(xk, wv.y, t1);
            t2 = fmaf(xk, wv.z, t2);
            t3 = fmaf(xk, wv.w, t3);
        }
        t0 = fmaxf(t0, 0.f); t1 = fmaxf(t1, 0.f);
        t2 = fmaxf(t2, 0.f); t3 = fmaxf(t3, 0.f);
#pragma unroll
        for (int c = 0; c < NC; ++c) {
            z[c] = fmaf(t0, sWl[jq * 4 + 0][c], z[c]);
            z[c] = fmaf(t1, sWl[jq * 4 + 1][c], z[c]);
            z[c] = fmaf(t2, sWl[jq * 4 + 2][c], z[c]);
            z[c] = fmaf(t3, sWl[jq * 4 + 3][c], z[c]);
        }
    }
#pragma unroll
    for (int c = 0; c < NC; ++c) Z[row * NC + c] = z[c];
}

// ================= CSR binning (once per call) =================
__global__ __launch_bounds__(256) void count_deg(
    const int* __restrict__ sx, const int* __restrict__ sy,
    int* __restrict__ deg, int m)
{
    int e = blockIdx.x * 256 + threadIdx.x;
    if (e >= m) return;
    atomicAdd(&deg[sx[e]], 1);
    atomicAdd(&deg[sy[e]], 1);
}

__global__ __launch_bounds__(256) void scan1(
    const int* __restrict__ deg, int* __restrict__ offs,
    int* __restrict__ bsum, int n)
{
    __shared__ int s[256];
    int t = threadIdx.x;
    int i = blockIdx.x * 256 + t;
    int v = (i < n) ? deg[i] : 0;
    s[t] = v;
    __syncthreads();
    for (int st = 1; st < 256; st <<= 1) {
        int tmp = (t >= st) ? s[t - st] : 0;
        __syncthreads();
        s[t] += tmp;
        __syncthreads();
    }
    if (i < n) offs[i] = s[t] - v;
    if (t == 255) bsum[blockIdx.x] = s[255];
}

__global__ __launch_bounds__(1024) void scan2(
    int* __restrict__ bsum, int* __restrict__ bbase, int nb)
{
    __shared__ int s[1024];
    int t = threadIdx.x;
    int v = (t < nb) ? bsum[t] : 0;
    s[t] = v;
    __syncthreads();
    for (int st = 1; st < 1024; st <<= 1) {
        int tmp = (t >= st) ? s[t - st] : 0;
        __syncthreads();
        s[t] += tmp;
        __syncthreads();
    }
    if (t < nb) bbase[t] = s[t] - v;
}

__global__ __launch_bounds__(256) void scan3(
    int* __restrict__ offs, const int* __restrict__ bbase,
    int* __restrict__ cur, int n)
{
    int i = blockIdx.x * 256 + threadIdx.x;
    if (i >= n) return;
    int o = offs[i] + bbase[blockIdx.x];
    offs[i] = o;
    cur[i] = o;
}

__global__ __launch_bounds__(256) void scatter_recs(
    const int* __restrict__ sx, const int* __restrict__ sy,
    const float* __restrict__ rel, int* __restrict__ cur,
    uint2* __restrict__ recs, int m)
{
    int e = blockIdx.x * 256 + threadIdx.x;
    if (e >= m) return;
    int x = sx[e], y = sy[e];
    unsigned rb = __float_as_uint(rel[e]);
    int px = atomicAdd(&cur[x], 1);
    recs[px] = make_uint2((unsigned)y, rb);
    int py = atomicAdd(&cur[y], 1);
    recs[py] = make_uint2((unsigned)x | 0x80000000u, rb);
}

// ============ KENN layer as pure gather (no atomics) ============
__global__ __launch_bounds__(256) void kenn_gather(
    const float* __restrict__ Zin, float* __restrict__ Zout,
    const int* __restrict__ offs, const int* __restrict__ deg,
    const uint2* __restrict__ recs, const float* __restrict__ cw,
    int n, int dofinal)
{
    int node = blockIdx.x * 256 + threadIdx.x;
    if (node >= n) return;

    float zown[NC], acc[NC], cwv[NC];
    const float2* pz = (const float2*)(Zin + 6L * node);
#pragma unroll
    for (int q = 0; q < 3; ++q) {
        float2 t = pz[q];
        zown[2 * q] = t.x; zown[2 * q + 1] = t.y;
    }
#pragma unroll
    for (int c = 0; c < NC; ++c) { acc[c] = zown[c]; cwv[c] = cw[c]; }

    const int start = offs[node];
    const int cnt = deg[node];

    for (int i = 0; i < cnt; ++i) {
        uint2 rc = recs[start + i];
        const int other = (int)(rc.x & 0x7FFFFFFFu);
        const bool sideY = (rc.x & 0x80000000u) != 0;
        const float l0 = -__uint_as_float(rc.y);

        float zo[NC];
        const float2* po = (const float2*)(Zin + 6L * other);
#pragma unroll
        for (int q = 0; q < 3; ++q) {
            float2 t = po[q];
            zo[2 * q] = t.x; zo[2 * q + 1] = t.y;
        }

#pragma unroll
        for (int c = 0; c < NC; ++c) {
            float zx = sideY ? zo[c] : zown[c];
            float zy = sideY ? zown[c] : zo[c];
            float l1 = -zx;
            float l2 = zy;
            float mx = fmaxf(l0, fmaxf(l1, l2));
            float e0 = __expf(l0 - mx);
            float e1 = __expf(l1 - mx);
            float e2 = __expf(l2 - mx);
            float g = cwv[c] / (e0 + e1 + e2);
            acc[c] += sideY ? (e2 * g) : (-e1 * g);
        }
    }

    if (dofinal) {
        float mx = acc[0];
#pragma unroll
        for (int c = 1; c < NC; ++c) mx = fmaxf(mx, acc[c]);
        float e[NC], s = 0.f;
#pragma unroll
        for (int c = 0; c < NC; ++c) { e[c] = __expf(acc[c] - mx); s += e[c]; }
        float inv = 1.f / s;
        float2* po = (float2*)(Zout + 6L * node);
#pragma unroll
        for (int q = 0; q < 3; ++q) {
            float2 t; t.x = e[2 * q] * inv; t.y = e[2 * q + 1] * inv;
            po[q] = t;
        }
    } else {
        float2* po = (float2*)(Zout + 6L * node);
#pragma unroll
        for (int q = 0; q < 3; ++q) {
            float2 t; t.x = acc[2 * q]; t.y = acc[2 * q + 1];
            po[q] = t;
        }
    }
}

// ---------------- fallback path kernels (atomic version) ----------------
__global__ __launch_bounds__(256) void kenn_edge(
    const float* __restrict__ Zold, float* __restrict__ Znew,
    const float* __restrict__ rel, const int* __restrict__ sx,
    const int* __restrict__ sy, const float* __restrict__ cw, int m)
{
    int idx = blockIdx.x * 256 + threadIdx.x;
    if (idx >= m) return;
    const int x = sx[idx];
    const int y = sy[idx];
    const float l0 = -rel[idx];

    float zx[NC], zy[NC];
    const float2* px = (const float2*)(Zold + 6L * x);
    const float2* py = (const float2*)(Zold + 6L * y);
#pragma unroll
    for (int q = 0; q < 3; ++q) {
        float2 t = px[q]; zx[2 * q] = t.x; zx[2 * q + 1] = t.y;
        float2 u = py[q]; zy[2 * q] = u.x; zy[2 * q + 1] = u.y;
    }
#pragma unroll
    for (int c = 0; c < NC; ++c) {
        float l1 = -zx[c];
        float l2 = zy[c];
        float mx = fmaxf(l0, fmaxf(l1, l2));
        float e0 = __expf(l0 - mx);
        float e1 = __expf(l1 - mx);
        float e2 = __expf(l2 - mx);
        float s = cw[c] / (e0 + e1 + e2);
        atomicAdd(&Znew[6L * x + c], -e1 * s);
        atomicAdd(&Znew[6L * y + c],  e2 * s);
    }
}

__global__ __launch_bounds__(256) void softmax6(
    const float* __restrict__ Z, float* __restrict__ out, int n)
{
    long row = (long)blockIdx.x * 256 + threadIdx.x;
    if (row >= n) return;
    float v[NC];
    const float2* p = (const float2*)(Z + row * 6);
#pragma unroll
    for (int q = 0; q < 3; ++q) { float2 t = p[q]; v[2 * q] = t.x; v[2 * q + 1] = t.y; }
    float mx = v[0];
#pragma unroll
    for (int c = 1; c < NC; ++c) mx = fmaxf(mx, v[c]);
    float e[NC], s = 0.f;
#pragma unroll
    for (int c = 0; c < NC; ++c) { e[c] = __expf(v[c] - mx); s += e[c]; }
    float inv = 1.f / s;
    float2* po = (float2*)(out + row * 6);
#pragma unroll
    for (int q = 0; q < 3; ++q) {
        float2 t; t.x = e[2 * q] * inv; t.y = e[2 * q + 1] * inv;
        po[q] = t;
    }
}

extern "C" void kernel_launch(void* const* d_in, const int* in_sizes, int n_in,
                              void* d_out, int out_size, void* d_ws, size_t ws_size,
                              hipStream_t stream)
{
    const float* F   = (const float*)d_in[0];
    const float* rel = (const float*)d_in[1];
    const int*   sx  = (const int*)d_in[2];
    const int*   sy  = (const int*)d_in[3];
    const float* W1  = (const float*)d_in[4];
    const float* b1  = (const float*)d_in[5];
    const float* W2  = (const float*)d_in[6];
    const float* b2  = (const float*)d_in[7];
    const float* W3  = (const float*)d_in[8];
    const float* b3  = (const float*)d_in[9];
    const float* Wl  = (const float*)d_in[10];
    const float* bl  = (const float*)d_in[11];
    const float* cw1 = (const float*)d_in[12];
    const float* cw2 = (const float*)d_in[13];
    const float* cw3 = (const float*)d_in[14];

    const int n = in_sizes[0] / D_FEAT;   // 100000
    const int m = in_sizes[1];            // 3200000

    // workspace layout
    float*  H    = (float*)d_ws;                     // n*HID
    float*  Z0   = H + (size_t)n * HID;              // n*6
    float*  Z1   = Z0 + (size_t)n * NC;              // n*6
    ushort* Whi  = (ushort*)(Z1 + (size_t)n * NC);   // 128*4*64*8 = 262144
    ushort* Wlo  = Whi + 262144;                     // 262144
    int* deg     = (int*)(Wlo + 262144);             // n
    int* offs    = deg + n;                          // n
    int* cur     = offs + n;                         // n
    int* bsum    = cur + n;                          // 1024
    int* bbase   = bsum + 1024;                      // 1024
    uint2* recs  = (uint2*)(bbase + 1024);           // 2m

    const size_t need = ((char*)(recs + 2 * (size_t)m)) - (char*)d_ws;

    prep_wfrag<<<1024, 256, 0, stream>>>(W1, Whi, Wlo);
    gemm1_mfma<<<(n + 127) / 128, 256, 0, stream>>>(F, Whi, Wlo, b1, H, n);
    mlp_tail<<<(n + 255) / 256, 256, 0, stream>>>(H, W2, b2, W3, b3, Wl, bl, Z0, n);

    const int nblk = (n + 255) / 256;
    const int eblk = (m + 255) / 256;

    if (ws_size >= need) {
        hipMemsetAsync(deg, 0, (size_t)n * sizeof(int), stream);
        count_deg<<<eblk, 256, 0, stream>>>(sx, sy, deg, m);
        scan1<<<nblk, 256, 0, stream>>>(deg, offs, bsum, n);
        scan2<<<1, 1024, 0, stream>>>(bsum, bbase, nblk);
        scan3<<<nblk, 256, 0, stream>>>(offs, bbase, cur, n);
        scatter_recs<<<eblk, 256, 0, stream>>>(sx, sy, rel, cur, recs, m);

        kenn_gather<<<nblk, 256, 0, stream>>>(Z0, Z1, offs, deg, recs, cw1, n, 0);
        kenn_gather<<<nblk, 256, 0, stream>>>(Z1, Z0, offs, deg, recs, cw2, n, 0);
        kenn_gather<<<nblk, 256, 0, stream>>>(Z0, (float*)d_out, offs, deg, recs, cw3, n, 1);
    } else {
        const size_t zbytes = (size_t)n * NC * sizeof(float);
        hipMemcpyAsync(Z1, Z0, zbytes, hipMemcpyDeviceToDevice, stream);
        kenn_edge<<<eblk, 256, 0, stream>>>(Z0, Z1, rel, sx, sy, cw1, m);
        hipMemcpyAsync(Z0, Z1, zbytes, hipMemcpyDeviceToDevice, stream);
        kenn_edge<<<eblk, 256, 0, stream>>>(Z1, Z0, rel, sx, sy, cw2, m);
        hipMemcpyAsync(Z1, Z0, zbytes, hipMemcpyDeviceToDevice, stream);
        kenn_edge<<<eblk, 256, 0, stream>>>(Z0, Z1, rel, sx, sy, cw3, m);
        softmax6<<<nblk, 256, 0, stream>>>(Z1, (float*)d_out, n);
    }
}

// Round 4
// 1045.385 us; speedup vs baseline: 6.9366x; 1.6975x over previous
//
#include <hip/hip_runtime.h>

#define D_FEAT 4096
#define HID 50
#define NC 6
#define BCAP 10240   // records per bucket region (avg ~8184, sigma ~90)

typedef __attribute__((ext_vector_type(8))) short bf16x8;
typedef __attribute__((ext_vector_type(4))) float f32x4;

// ============ W1 -> bf16 hi/lo MFMA B-fragment pre-pack ============
// frag idx: ((kc*4 + ct)*64 + l)*8 + j  ->  k = kc*32 + (l>>4)*8 + j,
//                                           c = ct*16 + (l&15)  (c>=50 -> 0)
__global__ __launch_bounds__(256) void prep_wfrag(
    const float* __restrict__ W1, ushort* __restrict__ Whi,
    ushort* __restrict__ Wlo)
{
    int idx = blockIdx.x * 256 + threadIdx.x;   // 0 .. 128*4*64*8-1
    int j  = idx & 7;
    int l  = (idx >> 3) & 63;
    int ct = (idx >> 9) & 3;
    int kc = idx >> 11;
    int k = kc * 32 + (l >> 4) * 8 + j;
    int c = ct * 16 + (l & 15);
    float v = (c < HID) ? W1[k * HID + c] : 0.f;
    unsigned b = __float_as_uint(v);
    unsigned h = (b + 0x8000u) >> 16;                 // round-half-up bf16
    float hf = __uint_as_float(h << 16);
    float lr = v - hf;
    unsigned lo = (__float_as_uint(lr) + 0x8000u) >> 16;
    Whi[idx] = (ushort)h;
    Wlo[idx] = (ushort)lo;
}

// ============ GEMM1 via MFMA bf16x3: H = relu(F @ W1 + b1) ============
// block = 256 thr = 4 waves; block tile 128 rows x 64 cols;
// wave tile 32 rows (2 mfma row-tiles) x 64 cols (4 col-tiles); K chunk 32.
__global__ __launch_bounds__(256) void gemm1_mfma(
    const float* __restrict__ F, const ushort* __restrict__ Whi,
    const ushort* __restrict__ Wlo, const float* __restrict__ b1,
    float* __restrict__ H, int nrows)
{
    const int tid = threadIdx.x;
    const int w  = tid >> 6;
    const int l  = tid & 63;
    const int l16 = l & 15, lq = l >> 4;
    const long rowb = (long)blockIdx.x * 128 + (long)w * 32;

    const float* fp[2];
#pragma unroll
    for (int rt = 0; rt < 2; ++rt) {
        long r = rowb + rt * 16 + l16;
        if (r > (long)nrows - 1) r = (long)nrows - 1;
        fp[rt] = F + r * (long)D_FEAT + lq * 8;
    }
    const bf16x8* bhip = (const bf16x8*)Whi + l;   // + kc*256 + ct*64
    const bf16x8* blop = (const bf16x8*)Wlo + l;

    f32x4 acc[2][4];
#pragma unroll
    for (int rt = 0; rt < 2; ++rt)
#pragma unroll
        for (int ct = 0; ct < 4; ++ct)
#pragma unroll
            for (int i = 0; i < 4; ++i) acc[rt][ct][i] = 0.f;

    // register double-buffer: preload chunk 0
    f32x4 an[2][2];
    bf16x8 bhn[4], bln[4];
#pragma unroll
    for (int rt = 0; rt < 2; ++rt) {
        an[rt][0] = *(const f32x4*)(fp[rt]);
        an[rt][1] = *(const f32x4*)(fp[rt] + 4);
    }
#pragma unroll
    for (int ct = 0; ct < 4; ++ct) { bhn[ct] = bhip[ct * 64]; bln[ct] = blop[ct * 64]; }

    union U4 { unsigned u[4]; bf16x8 v; };

    for (int kc = 0; kc < 128; ++kc) {
        f32x4 ac[2][2];
        bf16x8 bh[4], bl[4];
#pragma unroll
        for (int rt = 0; rt < 2; ++rt) { ac[rt][0] = an[rt][0]; ac[rt][1] = an[rt][1]; }
#pragma unroll
        for (int ct = 0; ct < 4; ++ct) { bh[ct] = bhn[ct]; bl[ct] = bln[ct]; }

        if (kc < 127) {
            const int kn = kc + 1;
#pragma unroll
            for (int rt = 0; rt < 2; ++rt) {
                an[rt][0] = *(const f32x4*)(fp[rt] + kn * 32);
                an[rt][1] = *(const f32x4*)(fp[rt] + kn * 32 + 4);
            }
#pragma unroll
            for (int ct = 0; ct < 4; ++ct) {
                bhn[ct] = bhip[kn * 256 + ct * 64];
                bln[ct] = blop[kn * 256 + ct * 64];
            }
        }

        // split A fp32 -> bf16 hi(trunc)/lo(trunc of residual); v_perm packing
        bf16x8 ahi[2], alo[2];
#pragma unroll
        for (int rt = 0; rt < 2; ++rt) {
            U4 hw, lw;
#pragma unroll
            for (int p = 0; p < 4; ++p) {
                float v0 = (p < 2) ? ac[rt][0][2 * p]     : ac[rt][1][2 * p - 4];
                float v1 = (p < 2) ? ac[rt][0][2 * p + 1] : ac[rt][1][2 * p - 3];
                unsigned b0 = __float_as_uint(v0), b1 = __float_as_uint(v1);
                hw.u[p] = __builtin_amdgcn_perm(b1, b0, 0x07060302u);
                float l0f = v0 - __uint_as_float(b0 & 0xFFFF0000u);
                float l1f = v1 - __uint_as_float(b1 & 0xFFFF0000u);
                lw.u[p] = __builtin_amdgcn_perm(__float_as_uint(l1f),
                                                __float_as_uint(l0f), 0x07060302u);
            }
            ahi[rt] = hw.v; alo[rt] = lw.v;
        }

#pragma unroll
        for (int rt = 0; rt < 2; ++rt)
#pragma unroll
            for (int ct = 0; ct < 4; ++ct) {
                acc[rt][ct] = __builtin_amdgcn_mfma_f32_16x16x32_bf16(ahi[rt], bh[ct], acc[rt][ct], 0, 0, 0);
                acc[rt][ct] = __builtin_amdgcn_mfma_f32_16x16x32_bf16(ahi[rt], bl[ct], acc[rt][ct], 0, 0, 0);
                acc[rt][ct] = __builtin_amdgcn_mfma_f32_16x16x32_bf16(alo[rt], bh[ct], acc[rt][ct], 0, 0, 0);
            }
    }

    // epilogue: D row = (lane>>4)*4 + i, col = ct*16 + (lane&15)
#pragma unroll
    for (int ct = 0; ct < 4; ++ct) {
        int col = ct * 16 + l16;
        if (col >= HID) continue;
        float bias = b1[col];
#pragma unroll
        for (int rt = 0; rt < 2; ++rt)
#pragma unroll
            for (int i = 0; i < 4; ++i) {
                long row = rowb + rt * 16 + lq * 4 + i;
                if (row < nrows) {
                    float v = acc[rt][ct][i] + bias;
                    H[row * HID + col] = v > 0.f ? v : 0.f;
                }
            }
    }
}

// ---------------- MLP tail (register-lean, no x3 array) ----------------
__global__ __launch_bounds__(256) void mlp_tail(
    const float* __restrict__ H,
    const float* __restrict__ W2, const float* __restrict__ b2,
    const float* __restrict__ W3, const float* __restrict__ b3,
    const float* __restrict__ Wl, const float* __restrict__ bl,
    float* __restrict__ Z, int n)
{
    __shared__ float sW2[HID][52];
    __shared__ float sW3[HID][52];
    __shared__ float sWl[52][8];
    __shared__ float sb2[52], sb3[52], sbl[8];

    for (int i = threadIdx.x; i < HID * 52; i += 256) {
        int r = i / 52, c = i % 52;
        sW2[r][c] = (c < HID) ? W2[r * HID + c] : 0.f;
        sW3[r][c] = (c < HID) ? W3[r * HID + c] : 0.f;
    }
    for (int i = threadIdx.x; i < 52 * 8; i += 256) {
        int r = i / 8, c = i % 8;
        sWl[r][c] = (r < HID && c < NC) ? Wl[r * NC + c] : 0.f;
    }
    if (threadIdx.x < 52) {
        sb2[threadIdx.x] = (threadIdx.x < HID) ? b2[threadIdx.x] : 0.f;
        sb3[threadIdx.x] = (threadIdx.x < HID) ? b3[threadIdx.x] : 0.f;
    }
    if (threadIdx.x < 8) sbl[threadIdx.x] = (threadIdx.x < NC) ? bl[threadIdx.x] : 0.f;
    __syncthreads();

    long row = (long)blockIdx.x * 256 + threadIdx.x;
    if (row >= n) return;

    float x1[HID];
#pragma unroll
    for (int i = 0; i < HID / 2; ++i) {
        float2 t = *(const float2*)(H + row * HID + 2 * i);
        x1[2 * i] = t.x; x1[2 * i + 1] = t.y;
    }

    float x2[52];
#pragma unroll
    for (int j = 0; j < 52; ++j) x2[j] = sb2[j];
    for (int i = 0; i < HID; ++i) {
        float xi = x1[i];
#pragma unroll
        for (int jq = 0; jq < 13; ++jq) {
            float4 t = *(const float4*)&sW2[i][jq * 4];
            x2[jq * 4 + 0] = fmaf(xi, t.x, x2[jq * 4 + 0]);
            x2[jq * 4 + 1] = fmaf(xi, t.y, x2[jq * 4 + 1]);
            x2[jq * 4 + 2] = fmaf(xi, t.z, x2[jq * 4 + 2]);
            x2[jq * 4 + 3] = fmaf(xi, t.w, x2[jq * 4 + 3]);
        }
    }
#pragma unroll
    for (int j = 0; j < 52; ++j) x2[j] = fmaxf(x2[j], 0.f);

    float z[NC];
#pragma unroll
    for (int c = 0; c < NC; ++c) z[c] = sbl[c];
    for (int jq = 0; jq < 13; ++jq) {
        float t0 = sb3[jq * 4 + 0], t1 = sb3[jq * 4 + 1];
        float t2 = sb3[jq * 4 + 2], t3 = sb3[jq * 4 + 3];
        for (int k = 0; k < HID; ++k) {
            float xk = x2[k];
            float4 wv = *(const float4*)&sW3[k][jq * 4];
            t0 = fmaf(xk, wv.x, t0);
            t1 = fmaf(xk, wv.y, t1);
            t2 = fmaf(xk, wv.z, t2);
            t3 = fmaf(xk, wv.w, t3);
        }
        t0 = fmaxf(t0, 0.f); t1 = fmaxf(t1, 0.f);
        t2 = fmaxf(t2, 0.f); t3 = fmaxf(t3, 0.f);
#pragma unroll
        for (int c = 0; c < NC; ++c) {
            z[c] = fmaf(t0, sWl[jq * 4 + 0][c], z[c]);
            z[c] = fmaf(t1, sWl[jq * 4 + 1][c], z[c]);
            z[c] = fmaf(t2, sWl[jq * 4 + 2][c], z[c]);
            z[c] = fmaf(t3, sWl[jq * 4 + 3][c], z[c]);
        }
    }
#pragma unroll
    for (int c = 0; c < NC; ++c) Z[row * NC + c] = z[c];
}

// ================= two-level bucket binning =================
// Pass 1: block-aggregated scatter into coarse buckets (node>>7).
// block = 1024 thr, 4096 edges (8192 endpoint-records) per block.
// One global returning atomic per (block,bucket): ~611K total vs 6.4M.
__global__ __launch_bounds__(1024) void scatter_bucket(
    const int* __restrict__ sx, const int* __restrict__ sy,
    const float* __restrict__ rel, int* __restrict__ cursor,
    uint2* __restrict__ pool, int m, int nbuck)
{
    __shared__ int hist[1024];
    __shared__ int gb[1024];
    const int t = threadIdx.x;
    hist[t] = 0;
    __syncthreads();

    const int e0 = blockIdx.x * 4096;
    unsigned rx[8], ry[8], pr[8];
#pragma unroll
    for (int k = 0; k < 4; ++k) {
        int e = e0 + k * 1024 + t;
        if (e < m) {
            int x = sx[e], y = sy[e];
            unsigned rb = __float_as_uint(rel[e]);
            int bA = x >> 7;
            int rA = atomicAdd(&hist[bA], 1);
            rx[2 * k] = (unsigned)(x & 127) | ((unsigned)y << 8);      // side 0
            ry[2 * k] = rb;
            pr[2 * k] = ((unsigned)bA << 22) | (unsigned)rA;
            int bB = y >> 7;
            int rB = atomicAdd(&hist[bB], 1);
            rx[2 * k + 1] = (unsigned)(y & 127) | 0x80u | ((unsigned)x << 8); // side 1
            ry[2 * k + 1] = rb;
            pr[2 * k + 1] = ((unsigned)bB << 22) | (unsigned)rB;
        } else {
            pr[2 * k] = 0xFFFFFFFFu; pr[2 * k + 1] = 0xFFFFFFFFu;
        }
    }
    __syncthreads();
    for (int b = t; b < nbuck; b += 1024) {
        int h = hist[b];
        gb[b] = h ? atomicAdd(&cursor[b], h) : 0;
    }
    __syncthreads();
#pragma unroll
    for (int k = 0; k < 8; ++k) {
        if (pr[k] == 0xFFFFFFFFu) continue;
        unsigned buck = pr[k] >> 22;
        unsigned rank = pr[k] & 0x3FFFFFu;
        unsigned slot = (unsigned)gb[buck] + rank;
        if (slot < BCAP)
            pool[(size_t)buck * BCAP + slot] = make_uint2(rx[k], ry[k]);
    }
}

// exclusive scan of clamped bucket counts (nb <= 1024)
__global__ __launch_bounds__(1024) void scan_buckets(
    const int* __restrict__ cursor, int* __restrict__ bucket_base, int nb)
{
    __shared__ int s[1024];
    int t = threadIdx.x;
    int v = 0;
    if (t < nb) { v = cursor[t]; if (v > BCAP) v = BCAP; }
    s[t] = v;
    __syncthreads();
    for (int st = 1; st < 1024; st <<= 1) {
        int tmp = (t >= st) ? s[t - st] : 0;
        __syncthreads();
        s[t] += tmp;
        __syncthreads();
    }
    if (t < nb) bucket_base[t] = s[t] - v;
}

// Pass 2: per-bucket LDS counting sort by node-in-bucket -> node CSR
__global__ __launch_bounds__(256) void sort_bucket(
    const uint2* __restrict__ pool, const int* __restrict__ cursor,
    const int* __restrict__ bucket_base, uint2* __restrict__ recs,
    int* __restrict__ offs, int* __restrict__ deg, int n)
{
    __shared__ int hist[128], nbase[128], cur[128];
    __shared__ int sc[128];
    const int b = blockIdx.x;
    const int t = threadIdx.x;
    int cnt = cursor[b]; if (cnt > BCAP) cnt = BCAP;
    const int base = bucket_base[b];
    if (t < 128) hist[t] = 0;
    __syncthreads();
    const uint2* bp = pool + (size_t)b * BCAP;
    for (int i = t; i < cnt; i += 256)
        atomicAdd(&hist[bp[i].x & 127u], 1);
    __syncthreads();
    int v = (t < 128) ? hist[t] : 0;
    if (t < 128) sc[t] = v;
    __syncthreads();
    for (int st = 1; st < 128; st <<= 1) {
        int tmp = (t >= st && t < 128) ? sc[t - st] : 0;
        __syncthreads();
        if (t < 128) sc[t] += tmp;
        __syncthreads();
    }
    if (t < 128) {
        nbase[t] = sc[t] - v;
        cur[t] = 0;
        int gnode = b * 128 + t;
        if (gnode < n) { offs[gnode] = base + sc[t] - v; deg[gnode] = v; }
    }
    __syncthreads();
    for (int i = t; i < cnt; i += 256) {
        uint2 r = bp[i];
        unsigned nl = r.x & 127u;
        unsigned side = (r.x >> 7) & 1u;
        unsigned other = r.x >> 8;
        int rk = atomicAdd(&cur[nl], 1);
        recs[base + nbase[nl] + rk] = make_uint2(other | (side << 31), r.y);
    }
}

// ============ KENN layer as pure gather (no atomics) ============
__global__ __launch_bounds__(256) void kenn_gather(
    const float* __restrict__ Zin, float* __restrict__ Zout,
    const int* __restrict__ offs, const int* __restrict__ deg,
    const uint2* __restrict__ recs, const float* __restrict__ cw,
    int n, int dofinal)
{
    int node = blockIdx.x * 256 + threadIdx.x;
    if (node >= n) return;

    float zown[NC], acc[NC], cwv[NC];
    const float2* pz = (const float2*)(Zin + 6L * node);
#pragma unroll
    for (int q = 0; q < 3; ++q) {
        float2 t = pz[q];
        zown[2 * q] = t.x; zown[2 * q + 1] = t.y;
    }
#pragma unroll
    for (int c = 0; c < NC; ++c) { acc[c] = zown[c]; cwv[c] = cw[c]; }

    const int start = offs[node];
    const int cnt = deg[node];

    for (int i = 0; i < cnt; ++i) {
        uint2 rc = recs[start + i];
        const int other = (int)(rc.x & 0x7FFFFFFFu);
        const bool sideY = (rc.x & 0x80000000u) != 0;
        const float l0 = -__uint_as_float(rc.y);

        float zo[NC];
        const float2* po = (const float2*)(Zin + 6L * other);
#pragma unroll
        for (int q = 0; q < 3; ++q) {
            float2 t = po[q];
            zo[2 * q] = t.x; zo[2 * q + 1] = t.y;
        }

#pragma unroll
        for (int c = 0; c < NC; ++c) {
            float zx = sideY ? zo[c] : zown[c];
            float zy = sideY ? zown[c] : zo[c];
            float l1 = -zx;
            float l2 = zy;
            float mx = fmaxf(l0, fmaxf(l1, l2));
            float e0 = __expf(l0 - mx);
            float e1 = __expf(l1 - mx);
            float e2 = __expf(l2 - mx);
            float g = cwv[c] / (e0 + e1 + e2);
            acc[c] += sideY ? (e2 * g) : (-e1 * g);
        }
    }

    if (dofinal) {
        float mx = acc[0];
#pragma unroll
        for (int c = 1; c < NC; ++c) mx = fmaxf(mx, acc[c]);
        float e[NC], s = 0.f;
#pragma unroll
        for (int c = 0; c < NC; ++c) { e[c] = __expf(acc[c] - mx); s += e[c]; }
        float inv = 1.f / s;
        float2* po = (float2*)(Zout + 6L * node);
#pragma unroll
        for (int q = 0; q < 3; ++q) {
            float2 t; t.x = e[2 * q] * inv; t.y = e[2 * q + 1] * inv;
            po[q] = t;
        }
    } else {
        float2* po = (float2*)(Zout + 6L * node);
#pragma unroll
        for (int q = 0; q < 3; ++q) {
            float2 t; t.x = acc[2 * q]; t.y = acc[2 * q + 1];
            po[q] = t;
        }
    }
}

// ---------------- fallback path kernels (atomic version) ----------------
__global__ __launch_bounds__(256) void kenn_edge(
    const float* __restrict__ Zold, float* __restrict__ Znew,
    const float* __restrict__ rel, const int* __restrict__ sx,
    const int* __restrict__ sy, const float* __restrict__ cw, int m)
{
    int idx = blockIdx.x * 256 + threadIdx.x;
    if (idx >= m) return;
    const int x = sx[idx];
    const int y = sy[idx];
    const float l0 = -rel[idx];

    float zx[NC], zy[NC];
    const float2* px = (const float2*)(Zold + 6L * x);
    const float2* py = (const float2*)(Zold + 6L * y);
#pragma unroll
    for (int q = 0; q < 3; ++q) {
        float2 t = px[q]; zx[2 * q] = t.x; zx[2 * q + 1] = t.y;
        float2 u = py[q]; zy[2 * q] = u.x; zy[2 * q + 1] = u.y;
    }
#pragma unroll
    for (int c = 0; c < NC; ++c) {
        float l1 = -zx[c];
        float l2 = zy[c];
        float mx = fmaxf(l0, fmaxf(l1, l2));
        float e0 = __expf(l0 - mx);
        float e1 = __expf(l1 - mx);
        float e2 = __expf(l2 - mx);
        float s = cw[c] / (e0 + e1 + e2);
        atomicAdd(&Znew[6L * x + c], -e1 * s);
        atomicAdd(&Znew[6L * y + c],  e2 * s);
    }
}

__global__ __launch_bounds__(256) void softmax6(
    const float* __restrict__ Z, float* __restrict__ out, int n)
{
    long row = (long)blockIdx.x * 256 + threadIdx.x;
    if (row >= n) return;
    float v[NC];
    const float2* p = (const float2*)(Z + row * 6);
#pragma unroll
    for (int q = 0; q < 3; ++q) { float2 t = p[q]; v[2 * q] = t.x; v[2 * q + 1] = t.y; }
    float mx = v[0];
#pragma unroll
    for (int c = 1; c < NC; ++c) mx = fmaxf(mx, v[c]);
    float e[NC], s = 0.f;
#pragma unroll
    for (int c = 0; c < NC; ++c) { e[c] = __expf(v[c] - mx); s += e[c]; }
    float inv = 1.f / s;
    float2* po = (float2*)(out + row * 6);
#pragma unroll
    for (int q = 0; q < 3; ++q) {
        float2 t; t.x = e[2 * q] * inv; t.y = e[2 * q + 1] * inv;
        po[q] = t;
    }
}

extern "C" void kernel_launch(void* const* d_in, const int* in_sizes, int n_in,
                              void* d_out, int out_size, void* d_ws, size_t ws_size,
                              hipStream_t stream)
{
    const float* F   = (const float*)d_in[0];
    const float* rel = (const float*)d_in[1];
    const int*   sx  = (const int*)d_in[2];
    const int*   sy  = (const int*)d_in[3];
    const float* W1  = (const float*)d_in[4];
    const float* b1  = (const float*)d_in[5];
    const float* W2  = (const float*)d_in[6];
    const float* b2  = (const float*)d_in[7];
    const float* W3  = (const float*)d_in[8];
    const float* b3  = (const float*)d_in[9];
    const float* Wl  = (const float*)d_in[10];
    const float* bl  = (const float*)d_in[11];
    const float* cw1 = (const float*)d_in[12];
    const float* cw2 = (const float*)d_in[13];
    const float* cw3 = (const float*)d_in[14];

    const int n = in_sizes[0] / D_FEAT;   // 100000
    const int m = in_sizes[1];            // 3200000
    const int nbuck = (n + 127) >> 7;     // 782

    // workspace layout (all segments 8B-aligned)
    float*  H    = (float*)d_ws;                     // n*HID
    float*  Z0   = H + (size_t)n * HID;              // n*6
    float*  Z1   = Z0 + (size_t)n * NC;              // n*6
    ushort* Whi  = (ushort*)(Z1 + (size_t)n * NC);   // 262144
    ushort* Wlo  = Whi + 262144;                     // 262144
    int* deg     = (int*)(Wlo + 262144);             // n
    int* offs    = deg + n;                          // n
    int* bbase   = offs + n;                         // 1024
    int* cursor  = bbase + 1024;                     // 1024 (nbuck used)
    uint2* recs  = (uint2*)(cursor + 1024);          // 2m
    uint2* pool  = recs + 2 * (size_t)m;             // nbuck*BCAP

    const size_t need = ((char*)(pool + (size_t)nbuck * BCAP)) - (char*)d_ws;

    prep_wfrag<<<1024, 256, 0, stream>>>(W1, Whi, Wlo);
    gemm1_mfma<<<(n + 127) / 128, 256, 0, stream>>>(F, Whi, Wlo, b1, H, n);
    mlp_tail<<<(n + 255) / 256, 256, 0, stream>>>(H, W2, b2, W3, b3, Wl, bl, Z0, n);

    const int nblk = (n + 255) / 256;
    const int eblk = (m + 255) / 256;

    if (ws_size >= need && nbuck <= 1024) {
        hipMemsetAsync(cursor, 0, (size_t)nbuck * sizeof(int), stream);
        scatter_bucket<<<(m + 4095) / 4096, 1024, 0, stream>>>(sx, sy, rel, cursor, pool, m, nbuck);
        scan_buckets<<<1, 1024, 0, stream>>>(cursor, bbase, nbuck);
        sort_bucket<<<nbuck, 256, 0, stream>>>(pool, cursor, bbase, recs, offs, deg, n);

        kenn_gather<<<nblk, 256, 0, stream>>>(Z0, Z1, offs, deg, recs, cw1, n, 0);
        kenn_gather<<<nblk, 256, 0, stream>>>(Z1, Z0, offs, deg, recs, cw2, n, 0);
        kenn_gather<<<nblk, 256, 0, stream>>>(Z0, (float*)d_out, offs, deg, recs, cw3, n, 1);
    } else {
        const size_t zbytes = (size_t)n * NC * sizeof(float);
        hipMemcpyAsync(Z1, Z0, zbytes, hipMemcpyDeviceToDevice, stream);
        kenn_edge<<<eblk, 256, 0, stream>>>(Z0, Z1, rel, sx, sy, cw1, m);
        hipMemcpyAsync(Z0, Z1, zbytes, hipMemcpyDeviceToDevice, stream);
        kenn_edge<<<eblk, 256, 0, stream>>>(Z1, Z0, rel, sx, sy, cw2, m);
        hipMemcpyAsync(Z1, Z0, zbytes, hipMemcpyDeviceToDevice, stream);
        kenn_edge<<<eblk, 256, 0, stream>>>(Z0, Z1, rel, sx, sy, cw3, m);
        softmax6<<<nblk, 256, 0, stream>>>(Z1, (float*)d_out, n);
    }
}

// Round 5
// 963.609 us; speedup vs baseline: 7.5253x; 1.0849x over previous
//
#include <hip/hip_runtime.h>

#define D_FEAT 4096
#define HID 50
#define NC 6
#define BCAP 10240   // records per bucket region (avg ~8184, sigma ~90)

typedef __attribute__((ext_vector_type(8))) short bf16x8;
typedef __attribute__((ext_vector_type(4))) float f32x4;

// ============ W1 -> bf16 hi/lo MFMA B-fragment pre-pack ============
// frag idx: ((kc*4 + ct)*64 + l)*8 + j  ->  k = kc*32 + (l>>4)*8 + j,
//                                           c = ct*16 + (l&15)  (c>=50 -> 0)
__global__ __launch_bounds__(256) void prep_wfrag(
    const float* __restrict__ W1, ushort* __restrict__ Whi,
    ushort* __restrict__ Wlo)
{
    int idx = blockIdx.x * 256 + threadIdx.x;   // 0 .. 128*4*64*8-1
    int j  = idx & 7;
    int l  = (idx >> 3) & 63;
    int ct = (idx >> 9) & 3;
    int kc = idx >> 11;
    int k = kc * 32 + (l >> 4) * 8 + j;
    int c = ct * 16 + (l & 15);
    float v = (c < HID) ? W1[k * HID + c] : 0.f;
    unsigned b = __float_as_uint(v);
    unsigned h = (b + 0x8000u) >> 16;                 // round-half-up bf16
    float hf = __uint_as_float(h << 16);
    float lr = v - hf;
    unsigned lo = (__float_as_uint(lr) + 0x8000u) >> 16;
    Whi[idx] = (ushort)h;
    Wlo[idx] = (ushort)lo;
}

// ---- helpers for GEMM1 ----
__device__ __forceinline__ void split_a(const f32x4 a0, const f32x4 a1,
                                        bf16x8& hi, bf16x8& lo)
{
    union U4 { unsigned u[4]; bf16x8 v; } hw, lw;
#pragma unroll
    for (int p = 0; p < 4; ++p) {
        float v0 = (p < 2) ? a0[2 * p]     : a1[2 * p - 4];
        float v1 = (p < 2) ? a0[2 * p + 1] : a1[2 * p - 3];
        unsigned b0 = __float_as_uint(v0), b1 = __float_as_uint(v1);
        hw.u[p] = __builtin_amdgcn_perm(b1, b0, 0x07060302u);
        float l0f = v0 - __uint_as_float(b0 & 0xFFFF0000u);
        float l1f = v1 - __uint_as_float(b1 & 0xFFFF0000u);
        lw.u[p] = __builtin_amdgcn_perm(__float_as_uint(l1f),
                                        __float_as_uint(l0f), 0x07060302u);
    }
    hi = hw.v; lo = lw.v;
}

__device__ __forceinline__ void mfma_step(f32x4 acc[2][4],
    const bf16x8 ahi[2], const bf16x8 alo[2],
    const bf16x8 bh[4], const bf16x8 bl[4])
{
#pragma unroll
    for (int rt = 0; rt < 2; ++rt)
#pragma unroll
        for (int ct = 0; ct < 4; ++ct) {
            acc[rt][ct] = __builtin_amdgcn_mfma_f32_16x16x32_bf16(ahi[rt], bh[ct], acc[rt][ct], 0, 0, 0);
            acc[rt][ct] = __builtin_amdgcn_mfma_f32_16x16x32_bf16(ahi[rt], bl[ct], acc[rt][ct], 0, 0, 0);
            acc[rt][ct] = __builtin_amdgcn_mfma_f32_16x16x32_bf16(alo[rt], bh[ct], acc[rt][ct], 0, 0, 0);
        }
}

// ============ GEMM1 via MFMA bf16x3: H = relu(F @ W1 + b1) ============
// block = 256 thr = 4 waves; block tile 128 rows x 64 cols;
// wave tile 32 rows (2 mfma row-tiles) x 64 cols (4 col-tiles); K chunk 32.
// Software pipeline: A prefetch depth 2 (ping-pong), B depth 1 (L2-hot).
__global__ __launch_bounds__(256) void gemm1_mfma(
    const float* __restrict__ F, const ushort* __restrict__ Whi,
    const ushort* __restrict__ Wlo, const float* __restrict__ b1,
    float* __restrict__ H, int nrows)
{
    const int tid = threadIdx.x;
    const int w  = tid >> 6;
    const int l  = tid & 63;
    const int l16 = l & 15, lq = l >> 4;
    const long rowb = (long)blockIdx.x * 128 + (long)w * 32;

    const float* fp[2];
#pragma unroll
    for (int rt = 0; rt < 2; ++rt) {
        long r = rowb + rt * 16 + l16;
        if (r > (long)nrows - 1) r = (long)nrows - 1;
        fp[rt] = F + r * (long)D_FEAT + lq * 8;
    }
    const bf16x8* bhip = (const bf16x8*)Whi + l;   // + kc*256 + ct*64
    const bf16x8* blop = (const bf16x8*)Wlo + l;

    f32x4 acc[2][4];
#pragma unroll
    for (int rt = 0; rt < 2; ++rt)
#pragma unroll
        for (int ct = 0; ct < 4; ++ct)
#pragma unroll
            for (int i = 0; i < 4; ++i) acc[rt][ct][i] = 0.f;

    // prologue: aA=A(0), aB=A(1), bA=B(0)
    f32x4 aA[2][2], aB[2][2];
    bf16x8 bhA[4], blA[4], bhB[4], blB[4];
#pragma unroll
    for (int rt = 0; rt < 2; ++rt) {
        aA[rt][0] = *(const f32x4*)(fp[rt]);
        aA[rt][1] = *(const f32x4*)(fp[rt] + 4);
        aB[rt][0] = *(const f32x4*)(fp[rt] + 32);
        aB[rt][1] = *(const f32x4*)(fp[rt] + 36);
    }
#pragma unroll
    for (int ct = 0; ct < 4; ++ct) { bhA[ct] = bhip[ct * 64]; blA[ct] = blop[ct * 64]; }

    for (int kc = 0; kc < 128; kc += 2) {
        // even: consume (aA,bA); prefetch B(kc+1)->bB, A(kc+2)->aA
        {
            bf16x8 ahi[2], alo[2];
            split_a(aA[0][0], aA[0][1], ahi[0], alo[0]);
            split_a(aA[1][0], aA[1][1], ahi[1], alo[1]);
            const int knb = kc + 1;
#pragma unroll
            for (int ct = 0; ct < 4; ++ct) {
                bhB[ct] = bhip[knb * 256 + ct * 64];
                blB[ct] = blop[knb * 256 + ct * 64];
            }
            const int kna = (kc + 2 < 128) ? kc + 2 : 127;
#pragma unroll
            for (int rt = 0; rt < 2; ++rt) {
                aA[rt][0] = *(const f32x4*)(fp[rt] + kna * 32);
                aA[rt][1] = *(const f32x4*)(fp[rt] + kna * 32 + 4);
            }
            mfma_step(acc, ahi, alo, bhA, blA);
        }
        // odd: consume (aB,bB); prefetch B(kc+2)->bA, A(kc+3)->aB
        {
            bf16x8 ahi[2], alo[2];
            split_a(aB[0][0], aB[0][1], ahi[0], alo[0]);
            split_a(aB[1][0], aB[1][1], ahi[1], alo[1]);
            const int knb = (kc + 2 < 128) ? kc + 2 : 127;
#pragma unroll
            for (int ct = 0; ct < 4; ++ct) {
                bhA[ct] = bhip[knb * 256 + ct * 64];
                blA[ct] = blop[knb * 256 + ct * 64];
            }
            const int kna = (kc + 3 < 128) ? kc + 3 : 127;
#pragma unroll
            for (int rt = 0; rt < 2; ++rt) {
                aB[rt][0] = *(const f32x4*)(fp[rt] + kna * 32);
                aB[rt][1] = *(const f32x4*)(fp[rt] + kna * 32 + 4);
            }
            mfma_step(acc, ahi, alo, bhB, blB);
        }
    }

    // epilogue: D row = (lane>>4)*4 + i, col = ct*16 + (lane&15)
#pragma unroll
    for (int ct = 0; ct < 4; ++ct) {
        int col = ct * 16 + l16;
        if (col >= HID) continue;
        float bias = b1[col];
#pragma unroll
        for (int rt = 0; rt < 2; ++rt)
#pragma unroll
            for (int i = 0; i < 4; ++i) {
                long row = rowb + rt * 16 + lq * 4 + i;
                if (row < nrows) {
                    float v = acc[rt][ct][i] + bias;
                    H[row * HID + col] = v > 0.f ? v : 0.f;
                }
            }
    }
}

// ---------------- MLP tail (register-lean, no x3 array) ----------------
__global__ __launch_bounds__(256) void mlp_tail(
    const float* __restrict__ H,
    const float* __restrict__ W2, const float* __restrict__ b2,
    const float* __restrict__ W3, const float* __restrict__ b3,
    const float* __restrict__ Wl, const float* __restrict__ bl,
    float* __restrict__ Z, int n)
{
    __shared__ float sW2[HID][52];
    __shared__ float sW3[HID][52];
    __shared__ float sWl[52][8];
    __shared__ float sb2[52], sb3[52], sbl[8];

    for (int i = threadIdx.x; i < HID * 52; i += 256) {
        int r = i / 52, c = i % 52;
        sW2[r][c] = (c < HID) ? W2[r * HID + c] : 0.f;
        sW3[r][c] = (c < HID) ? W3[r * HID + c] : 0.f;
    }
    for (int i = threadIdx.x; i < 52 * 8; i += 256) {
        int r = i / 8, c = i % 8;
        sWl[r][c] = (r < HID && c < NC) ? Wl[r * NC + c] : 0.f;
    }
    if (threadIdx.x < 52) {
        sb2[threadIdx.x] = (threadIdx.x < HID) ? b2[threadIdx.x] : 0.f;
        sb3[threadIdx.x] = (threadIdx.x < HID) ? b3[threadIdx.x] : 0.f;
    }
    if (threadIdx.x < 8) sbl[threadIdx.x] = (threadIdx.x < NC) ? bl[threadIdx.x] : 0.f;
    __syncthreads();

    long row = (long)blockIdx.x * 256 + threadIdx.x;
    if (row >= n) return;

    float x1[HID];
#pragma unroll
    for (int i = 0; i < HID / 2; ++i) {
        float2 t = *(const float2*)(H + row * HID + 2 * i);
        x1[2 * i] = t.x; x1[2 * i + 1] = t.y;
    }

    float x2[52];
#pragma unroll
    for (int j = 0; j < 52; ++j) x2[j] = sb2[j];
    for (int i = 0; i < HID; ++i) {
        float xi = x1[i];
#pragma unroll
        for (int jq = 0; jq < 13; ++jq) {
            float4 t = *(const float4*)&sW2[i][jq * 4];
            x2[jq * 4 + 0] = fmaf(xi, t.x, x2[jq * 4 + 0]);
            x2[jq * 4 + 1] = fmaf(xi, t.y, x2[jq * 4 + 1]);
            x2[jq * 4 + 2] = fmaf(xi, t.z, x2[jq * 4 + 2]);
            x2[jq * 4 + 3] = fmaf(xi, t.w, x2[jq * 4 + 3]);
        }
    }
#pragma unroll
    for (int j = 0; j < 52; ++j) x2[j] = fmaxf(x2[j], 0.f);

    float z[NC];
#pragma unroll
    for (int c = 0; c < NC; ++c) z[c] = sbl[c];
    for (int jq = 0; jq < 13; ++jq) {
        float t0 = sb3[jq * 4 + 0], t1 = sb3[jq * 4 + 1];
        float t2 = sb3[jq * 4 + 2], t3 = sb3[jq * 4 + 3];
        for (int k = 0; k < HID; ++k) {
            float xk = x2[k];
            float4 wv = *(const float4*)&sW3[k][jq * 4];
            t0 = fmaf(xk, wv.x, t0);
            t1 = fmaf(xk, wv.y, t1);
            t2 = fmaf(xk, wv.z, t2);
            t3 = fmaf(xk, wv.w, t3);
        }
        t0 = fmaxf(t0, 0.f); t1 = fmaxf(t1, 0.f);
        t2 = fmaxf(t2, 0.f); t3 = fmaxf(t3, 0.f);
#pragma unroll
        for (int c = 0; c < NC; ++c) {
            z[c] = fmaf(t0, sWl[jq * 4 + 0][c], z[c]);
            z[c] = fmaf(t1, sWl[jq * 4 + 1][c], z[c]);
            z[c] = fmaf(t2, sWl[jq * 4 + 2][c], z[c]);
            z[c] = fmaf(t3, sWl[jq * 4 + 3][c], z[c]);
        }
    }
#pragma unroll
    for (int c = 0; c < NC; ++c) Z[row * NC + c] = z[c];
}

// ================= two-level bucket binning =================
// Pass 1: block-aggregated scatter into coarse buckets (node>>7).
// block = 1024 thr, 8192 edges (16384 endpoint-records) per block.
// One global returning atomic per (block,bucket): ~306K total.
__global__ __launch_bounds__(1024) void scatter_bucket(
    const int* __restrict__ sx, const int* __restrict__ sy,
    const float* __restrict__ rel, int* __restrict__ cursor,
    uint2* __restrict__ pool, int m, int nbuck)
{
    __shared__ int hist[1024];
    __shared__ int gb[1024];
    const int t = threadIdx.x;
    hist[t] = 0;
    __syncthreads();

    const int e0 = blockIdx.x * 8192;
    unsigned rx[16], ry[16], pr[16];
#pragma unroll
    for (int k = 0; k < 8; ++k) {
        int e = e0 + k * 1024 + t;
        if (e < m) {
            int x = sx[e], y = sy[e];
            unsigned rb = __float_as_uint(rel[e]);
            int bA = x >> 7;
            int rA = atomicAdd(&hist[bA], 1);
            rx[2 * k] = (unsigned)(x & 127) | ((unsigned)y << 8);      // side 0
            ry[2 * k] = rb;
            pr[2 * k] = ((unsigned)bA << 22) | (unsigned)rA;
            int bB = y >> 7;
            int rB = atomicAdd(&hist[bB], 1);
            rx[2 * k + 1] = (unsigned)(y & 127) | 0x80u | ((unsigned)x << 8); // side 1
            ry[2 * k + 1] = rb;
            pr[2 * k + 1] = ((unsigned)bB << 22) | (unsigned)rB;
        } else {
            pr[2 * k] = 0xFFFFFFFFu; pr[2 * k + 1] = 0xFFFFFFFFu;
        }
    }
    __syncthreads();
    for (int b = t; b < nbuck; b += 1024) {
        int h = hist[b];
        gb[b] = h ? atomicAdd(&cursor[b], h) : 0;
    }
    __syncthreads();
#pragma unroll
    for (int k = 0; k < 16; ++k) {
        if (pr[k] == 0xFFFFFFFFu) continue;
        unsigned buck = pr[k] >> 22;
        unsigned rank = pr[k] & 0x3FFFFFu;
        unsigned slot = (unsigned)gb[buck] + rank;
        if (slot < BCAP)
            pool[(size_t)buck * BCAP + slot] = make_uint2(rx[k], ry[k]);
    }
}

// exclusive scan of clamped bucket counts (nb <= 1024)
__global__ __launch_bounds__(1024) void scan_buckets(
    const int* __restrict__ cursor, int* __restrict__ bucket_base, int nb)
{
    __shared__ int s[1024];
    int t = threadIdx.x;
    int v = 0;
    if (t < nb) { v = cursor[t]; if (v > BCAP) v = BCAP; }
    s[t] = v;
    __syncthreads();
    for (int st = 1; st < 1024; st <<= 1) {
        int tmp = (t >= st) ? s[t - st] : 0;
        __syncthreads();
        s[t] += tmp;
        __syncthreads();
    }
    if (t < nb) bucket_base[t] = s[t] - v;
}

// Pass 2: per-bucket LDS counting sort by node-in-bucket -> node CSR
__global__ __launch_bounds__(256) void sort_bucket(
    const uint2* __restrict__ pool, const int* __restrict__ cursor,
    const int* __restrict__ bucket_base, uint2* __restrict__ recs,
    int* __restrict__ offs, int* __restrict__ deg, int n)
{
    __shared__ int hist[128], nbase[128], cur[128];
    __shared__ int sc[128];
    const int b = blockIdx.x;
    const int t = threadIdx.x;
    int cnt = cursor[b]; if (cnt > BCAP) cnt = BCAP;
    const int base = bucket_base[b];
    if (t < 128) hist[t] = 0;
    __syncthreads();
    const uint2* bp = pool + (size_t)b * BCAP;
    for (int i = t; i < cnt; i += 256)
        atomicAdd(&hist[bp[i].x & 127u], 1);
    __syncthreads();
    int v = (t < 128) ? hist[t] : 0;
    if (t < 128) sc[t] = v;
    __syncthreads();
    for (int st = 1; st < 128; st <<= 1) {
        int tmp = (t >= st && t < 128) ? sc[t - st] : 0;
        __syncthreads();
        if (t < 128) sc[t] += tmp;
        __syncthreads();
    }
    if (t < 128) {
        nbase[t] = sc[t] - v;
        cur[t] = 0;
        int gnode = b * 128 + t;
        if (gnode < n) { offs[gnode] = base + sc[t] - v; deg[gnode] = v; }
    }
    __syncthreads();
    for (int i = t; i < cnt; i += 256) {
        uint2 r = bp[i];
        unsigned nl = r.x & 127u;
        unsigned side = (r.x >> 7) & 1u;
        unsigned other = r.x >> 8;
        int rk = atomicAdd(&cur[nl], 1);
        recs[base + nbase[nl] + rk] = make_uint2(other | (side << 31), r.y);
    }
}

// ============ KENN layer as pure gather (no atomics) ============
__global__ __launch_bounds__(256) void kenn_gather(
    const float* __restrict__ Zin, float* __restrict__ Zout,
    const int* __restrict__ offs, const int* __restrict__ deg,
    const uint2* __restrict__ recs, const float* __restrict__ cw,
    int n, int dofinal)
{
    int node = blockIdx.x * 256 + threadIdx.x;
    if (node >= n) return;

    float zown[NC], acc[NC], cwv[NC];
    const float2* pz = (const float2*)(Zin + 6L * node);
#pragma unroll
    for (int q = 0; q < 3; ++q) {
        float2 t = pz[q];
        zown[2 * q] = t.x; zown[2 * q + 1] = t.y;
    }
#pragma unroll
    for (int c = 0; c < NC; ++c) { acc[c] = zown[c]; cwv[c] = cw[c]; }

    const int start = offs[node];
    const int cnt = deg[node];

#pragma unroll 2
    for (int i = 0; i < cnt; ++i) {
        uint2 rc = recs[start + i];
        const int other = (int)(rc.x & 0x7FFFFFFFu);
        const bool sideY = (rc.x & 0x80000000u) != 0;
        const float l0 = -__uint_as_float(rc.y);

        float zo[NC];
        const float2* po = (const float2*)(Zin + 6L * other);
#pragma unroll
        for (int q = 0; q < 3; ++q) {
            float2 t = po[q];
            zo[2 * q] = t.x; zo[2 * q + 1] = t.y;
        }

#pragma unroll
        for (int c = 0; c < NC; ++c) {
            float zx = sideY ? zo[c] : zown[c];
            float zy = sideY ? zown[c] : zo[c];
            float l1 = -zx;
            float l2 = zy;
            float mx = fmaxf(l0, fmaxf(l1, l2));
            float e0 = __expf(l0 - mx);
            float e1 = __expf(l1 - mx);
            float e2 = __expf(l2 - mx);
            float g = cwv[c] / (e0 + e1 + e2);
            acc[c] += sideY ? (e2 * g) : (-e1 * g);
        }
    }

    if (dofinal) {
        float mx = acc[0];
#pragma unroll
        for (int c = 1; c < NC; ++c) mx = fmaxf(mx, acc[c]);
        float e[NC], s = 0.f;
#pragma unroll
        for (int c = 0; c < NC; ++c) { e[c] = __expf(acc[c] - mx); s += e[c]; }
        float inv = 1.f / s;
        float2* po = (float2*)(Zout + 6L * node);
#pragma unroll
        for (int q = 0; q < 3; ++q) {
            float2 t; t.x = e[2 * q] * inv; t.y = e[2 * q + 1] * inv;
            po[q] = t;
        }
    } else {
        float2* po = (float2*)(Zout + 6L * node);
#pragma unroll
        for (int q = 0; q < 3; ++q) {
            float2 t; t.x = acc[2 * q]; t.y = acc[2 * q + 1];
            po[q] = t;
        }
    }
}

// ---------------- fallback path kernels (atomic version) ----------------
__global__ __launch_bounds__(256) void kenn_edge(
    const float* __restrict__ Zold, float* __restrict__ Znew,
    const float* __restrict__ rel, const int* __restrict__ sx,
    const int* __restrict__ sy, const float* __restrict__ cw, int m)
{
    int idx = blockIdx.x * 256 + threadIdx.x;
    if (idx >= m) return;
    const int x = sx[idx];
    const int y = sy[idx];
    const float l0 = -rel[idx];

    float zx[NC], zy[NC];
    const float2* px = (const float2*)(Zold + 6L * x);
    const float2* py = (const float2*)(Zold + 6L * y);
#pragma unroll
    for (int q = 0; q < 3; ++q) {
        float2 t = px[q]; zx[2 * q] = t.x; zx[2 * q + 1] = t.y;
        float2 u = py[q]; zy[2 * q] = u.x; zy[2 * q + 1] = u.y;
    }
#pragma unroll
    for (int c = 0; c < NC; ++c) {
        float l1 = -zx[c];
        float l2 = zy[c];
        float mx = fmaxf(l0, fmaxf(l1, l2));
        float e0 = __expf(l0 - mx);
        float e1 = __expf(l1 - mx);
        float e2 = __expf(l2 - mx);
        float s = cw[c] / (e0 + e1 + e2);
        atomicAdd(&Znew[6L * x + c], -e1 * s);
        atomicAdd(&Znew[6L * y + c],  e2 * s);
    }
}

__global__ __launch_bounds__(256) void softmax6(
    const float* __restrict__ Z, float* __restrict__ out, int n)
{
    long row = (long)blockIdx.x * 256 + threadIdx.x;
    if (row >= n) return;
    float v[NC];
    const float2* p = (const float2*)(Z + row * 6);
#pragma unroll
    for (int q = 0; q < 3; ++q) { float2 t = p[q]; v[2 * q] = t.x; v[2 * q + 1] = t.y; }
    float mx = v[0];
#pragma unroll
    for (int c = 1; c < NC; ++c) mx = fmaxf(mx, v[c]);
    float e[NC], s = 0.f;
#pragma unroll
    for (int c = 0; c < NC; ++c) { e[c] = __expf(v[c] - mx); s += e[c]; }
    float inv = 1.f / s;
    float2* po = (float2*)(out + row * 6);
#pragma unroll
    for (int q = 0; q < 3; ++q) {
        float2 t; t.x = e[2 * q] * inv; t.y = e[2 * q + 1] * inv;
        po[q] = t;
    }
}

extern "C" void kernel_launch(void* const* d_in, const int* in_sizes, int n_in,
                              void* d_out, int out_size, void* d_ws, size_t ws_size,
                              hipStream_t stream)
{
    const float* F   = (const float*)d_in[0];
    const float* rel = (const float*)d_in[1];
    const int*   sx  = (const int*)d_in[2];
    const int*   sy  = (const int*)d_in[3];
    const float* W1  = (const float*)d_in[4];
    const float* b1  = (const float*)d_in[5];
    const float* W2  = (const float*)d_in[6];
    const float* b2  = (const float*)d_in[7];
    const float* W3  = (const float*)d_in[8];
    const float* b3  = (const float*)d_in[9];
    const float* Wl  = (const float*)d_in[10];
    const float* bl  = (const float*)d_in[11];
    const float* cw1 = (const float*)d_in[12];
    const float* cw2 = (const float*)d_in[13];
    const float* cw3 = (const float*)d_in[14];

    const int n = in_sizes[0] / D_FEAT;   // 100000
    const int m = in_sizes[1];            // 3200000
    const int nbuck = (n + 127) >> 7;     // 782

    // workspace layout (all segments 8B-aligned)
    float*  H    = (float*)d_ws;                     // n*HID
    float*  Z0   = H + (size_t)n * HID;              // n*6
    float*  Z1   = Z0 + (size_t)n * NC;              // n*6
    ushort* Whi  = (ushort*)(Z1 + (size_t)n * NC);   // 262144
    ushort* Wlo  = Whi + 262144;                     // 262144
    int* deg     = (int*)(Wlo + 262144);             // n
    int* offs    = deg + n;                          // n
    int* bbase   = offs + n;                         // 1024
    int* cursor  = bbase + 1024;                     // 1024 (nbuck used)
    uint2* recs  = (uint2*)(cursor + 1024);          // 2m
    uint2* pool  = recs + 2 * (size_t)m;             // nbuck*BCAP

    const size_t need = ((char*)(pool + (size_t)nbuck * BCAP)) - (char*)d_ws;

    prep_wfrag<<<1024, 256, 0, stream>>>(W1, Whi, Wlo);
    gemm1_mfma<<<(n + 127) / 128, 256, 0, stream>>>(F, Whi, Wlo, b1, H, n);
    mlp_tail<<<(n + 255) / 256, 256, 0, stream>>>(H, W2, b2, W3, b3, Wl, bl, Z0, n);

    const int nblk = (n + 255) / 256;
    const int eblk = (m + 255) / 256;

    if (ws_size >= need && nbuck <= 1024) {
        hipMemsetAsync(cursor, 0, (size_t)nbuck * sizeof(int), stream);
        scatter_bucket<<<(m + 8191) / 8192, 1024, 0, stream>>>(sx, sy, rel, cursor, pool, m, nbuck);
        scan_buckets<<<1, 1024, 0, stream>>>(cursor, bbase, nbuck);
        sort_bucket<<<nbuck, 256, 0, stream>>>(pool, cursor, bbase, recs, offs, deg, n);

        kenn_gather<<<nblk, 256, 0, stream>>>(Z0, Z1, offs, deg, recs, cw1, n, 0);
        kenn_gather<<<nblk, 256, 0, stream>>>(Z1, Z0, offs, deg, recs, cw2, n, 0);
        kenn_gather<<<nblk, 256, 0, stream>>>(Z0, (float*)d_out, offs, deg, recs, cw3, n, 1);
    } else {
        const size_t zbytes = (size_t)n * NC * sizeof(float);
        hipMemcpyAsync(Z1, Z0, zbytes, hipMemcpyDeviceToDevice, stream);
        kenn_edge<<<eblk, 256, 0, stream>>>(Z0, Z1, rel, sx, sy, cw1, m);
        hipMemcpyAsync(Z0, Z1, zbytes, hipMemcpyDeviceToDevice, stream);
        kenn_edge<<<eblk, 256, 0, stream>>>(Z1, Z0, rel, sx, sy, cw2, m);
        hipMemcpyAsync(Z1, Z0, zbytes, hipMemcpyDeviceToDevice, stream);
        kenn_edge<<<eblk, 256, 0, stream>>>(Z0, Z1, rel, sx, sy, cw3, m);
        softmax6<<<nblk, 256, 0, stream>>>(Z1, (float*)d_out, n);
    }
}

// Round 6
// 911.713 us; speedup vs baseline: 7.9536x; 1.0569x over previous
//
#include <hip/hip_runtime.h>

#define D_FEAT 4096
#define HID 50
#define NC 6
#define BCAP 10240   // records per bucket region (avg ~8184)

typedef __attribute__((ext_vector_type(8))) short bf16x8;
typedef __attribute__((ext_vector_type(4))) float f32x4;

// ============ W1 -> bf16 hi/lo MFMA B-fragment pre-pack ============
// frag idx: ((kc*4 + ct)*64 + l)*8 + j  ->  k = kc*32 + (l>>4)*8 + j,
//                                           c = ct*16 + (l&15)  (c>=50 -> 0)
__global__ __launch_bounds__(256) void prep_wfrag(
    const float* __restrict__ W1, ushort* __restrict__ Whi,
    ushort* __restrict__ Wlo)
{
    int idx = blockIdx.x * 256 + threadIdx.x;   // 0 .. 128*4*64*8-1
    int j  = idx & 7;
    int l  = (idx >> 3) & 63;
    int ct = (idx >> 9) & 3;
    int kc = idx >> 11;
    int k = kc * 32 + (l >> 4) * 8 + j;
    int c = ct * 16 + (l & 15);
    float v = (c < HID) ? W1[k * HID + c] : 0.f;
    unsigned b = __float_as_uint(v);
    unsigned h = (b + 0x8000u) >> 16;                 // round-half-up bf16
    float hf = __uint_as_float(h << 16);
    float lr = v - hf;
    unsigned lo = (__float_as_uint(lr) + 0x8000u) >> 16;
    Whi[idx] = (ushort)h;
    Wlo[idx] = (ushort)lo;
}

// ---- A fp32 -> bf16 hi(trunc)/lo(trunc residual), v_perm packed ----
__device__ __forceinline__ void split_a(const f32x4 a0, const f32x4 a1,
                                        bf16x8& hi, bf16x8& lo)
{
    union U4 { unsigned u[4]; bf16x8 v; } hw, lw;
#pragma unroll
    for (int p = 0; p < 4; ++p) {
        float v0 = (p < 2) ? a0[2 * p]     : a1[2 * p - 4];
        float v1 = (p < 2) ? a0[2 * p + 1] : a1[2 * p - 3];
        unsigned b0 = __float_as_uint(v0), b1 = __float_as_uint(v1);
        hw.u[p] = __builtin_amdgcn_perm(b1, b0, 0x07060302u);
        float l0f = v0 - __uint_as_float(b0 & 0xFFFF0000u);
        float l1f = v1 - __uint_as_float(b1 & 0xFFFF0000u);
        lw.u[p] = __builtin_amdgcn_perm(__float_as_uint(l1f),
                                        __float_as_uint(l0f), 0x07060302u);
    }
    hi = hw.v; lo = lw.v;
}

// ============ GEMM1 via MFMA bf16x3: H = relu(F @ W1 + b1) ============
// Lean occupancy-first version: depth-1 buffers, <=128 VGPR target
// (4 blocks/CU -> all 782 blocks resident; TLP hides HBM latency).
// block = 256 thr = 4 waves; block tile 128 rows x 64 cols;
// wave tile 32 rows (2 mfma row-tiles) x 64 cols (4 col-tiles); K chunk 32.
__global__ __launch_bounds__(256, 4) void gemm1_mfma(
    const float* __restrict__ F, const ushort* __restrict__ Whi,
    const ushort* __restrict__ Wlo, const float* __restrict__ b1,
    float* __restrict__ H, int nrows)
{
    const int tid = threadIdx.x;
    const int w  = tid >> 6;
    const int l  = tid & 63;
    const int l16 = l & 15, lq = l >> 4;
    const long rowb = (long)blockIdx.x * 128 + (long)w * 32;

    const float* fp[2];
#pragma unroll
    for (int rt = 0; rt < 2; ++rt) {
        long r = rowb + rt * 16 + l16;
        if (r > (long)nrows - 1) r = (long)nrows - 1;
        fp[rt] = F + r * (long)D_FEAT + lq * 8;
    }
    const bf16x8* bhip = (const bf16x8*)Whi + l;   // + kc*256 + ct*64
    const bf16x8* blop = (const bf16x8*)Wlo + l;

    f32x4 acc[2][4];
#pragma unroll
    for (int rt = 0; rt < 2; ++rt)
#pragma unroll
        for (int ct = 0; ct < 4; ++ct)
#pragma unroll
            for (int i = 0; i < 4; ++i) acc[rt][ct][i] = 0.f;

#pragma unroll 2
    for (int kc = 0; kc < 128; ++kc) {
        f32x4 a[2][2];
#pragma unroll
        for (int rt = 0; rt < 2; ++rt) {
            a[rt][0] = *(const f32x4*)(fp[rt] + kc * 32);
            a[rt][1] = *(const f32x4*)(fp[rt] + kc * 32 + 4);
        }
        bf16x8 bh[4], bl[4];
#pragma unroll
        for (int ct = 0; ct < 4; ++ct) {
            bh[ct] = bhip[kc * 256 + ct * 64];
            bl[ct] = blop[kc * 256 + ct * 64];
        }
        bf16x8 ahi[2], alo[2];
        split_a(a[0][0], a[0][1], ahi[0], alo[0]);
        split_a(a[1][0], a[1][1], ahi[1], alo[1]);
#pragma unroll
        for (int rt = 0; rt < 2; ++rt)
#pragma unroll
            for (int ct = 0; ct < 4; ++ct) {
                acc[rt][ct] = __builtin_amdgcn_mfma_f32_16x16x32_bf16(ahi[rt], bh[ct], acc[rt][ct], 0, 0, 0);
                acc[rt][ct] = __builtin_amdgcn_mfma_f32_16x16x32_bf16(ahi[rt], bl[ct], acc[rt][ct], 0, 0, 0);
                acc[rt][ct] = __builtin_amdgcn_mfma_f32_16x16x32_bf16(alo[rt], bh[ct], acc[rt][ct], 0, 0, 0);
            }
    }

    // epilogue: D row = (lane>>4)*4 + i, col = ct*16 + (lane&15)
#pragma unroll
    for (int ct = 0; ct < 4; ++ct) {
        int col = ct * 16 + l16;
        if (col >= HID) continue;
        float bias = b1[col];
#pragma unroll
        for (int rt = 0; rt < 2; ++rt)
#pragma unroll
            for (int i = 0; i < 4; ++i) {
                long row = rowb + rt * 16 + lq * 4 + i;
                if (row < nrows) {
                    float v = acc[rt][ct][i] + bias;
                    H[row * HID + col] = v > 0.f ? v : 0.f;
                }
            }
    }
}

// ---------------- MLP tail (register-lean, no x3 array) ----------------
__global__ __launch_bounds__(256) void mlp_tail(
    const float* __restrict__ H,
    const float* __restrict__ W2, const float* __restrict__ b2,
    const float* __restrict__ W3, const float* __restrict__ b3,
    const float* __restrict__ Wl, const float* __restrict__ bl,
    float* __restrict__ Z, int n)
{
    __shared__ float sW2[HID][52];
    __shared__ float sW3[HID][52];
    __shared__ float sWl[52][8];
    __shared__ float sb2[52], sb3[52], sbl[8];

    for (int i = threadIdx.x; i < HID * 52; i += 256) {
        int r = i / 52, c = i % 52;
        sW2[r][c] = (c < HID) ? W2[r * HID + c] : 0.f;
        sW3[r][c] = (c < HID) ? W3[r * HID + c] : 0.f;
    }
    for (int i = threadIdx.x; i < 52 * 8; i += 256) {
        int r = i / 8, c = i % 8;
        sWl[r][c] = (r < HID && c < NC) ? Wl[r * NC + c] : 0.f;
    }
    if (threadIdx.x < 52) {
        sb2[threadIdx.x] = (threadIdx.x < HID) ? b2[threadIdx.x] : 0.f;
        sb3[threadIdx.x] = (threadIdx.x < HID) ? b3[threadIdx.x] : 0.f;
    }
    if (threadIdx.x < 8) sbl[threadIdx.x] = (threadIdx.x < NC) ? bl[threadIdx.x] : 0.f;
    __syncthreads();

    long row = (long)blockIdx.x * 256 + threadIdx.x;
    if (row >= n) return;

    float x1[HID];
#pragma unroll
    for (int i = 0; i < HID / 2; ++i) {
        float2 t = *(const float2*)(H + row * HID + 2 * i);
        x1[2 * i] = t.x; x1[2 * i + 1] = t.y;
    }

    float x2[52];
#pragma unroll
    for (int j = 0; j < 52; ++j) x2[j] = sb2[j];
    for (int i = 0; i < HID; ++i) {
        float xi = x1[i];
#pragma unroll
        for (int jq = 0; jq < 13; ++jq) {
            float4 t = *(const float4*)&sW2[i][jq * 4];
            x2[jq * 4 + 0] = fmaf(xi, t.x, x2[jq * 4 + 0]);
            x2[jq * 4 + 1] = fmaf(xi, t.y, x2[jq * 4 + 1]);
            x2[jq * 4 + 2] = fmaf(xi, t.z, x2[jq * 4 + 2]);
            x2[jq * 4 + 3] = fmaf(xi, t.w, x2[jq * 4 + 3]);
        }
    }
#pragma unroll
    for (int j = 0; j < 52; ++j) x2[j] = fmaxf(x2[j], 0.f);

    float z[NC];
#pragma unroll
    for (int c = 0; c < NC; ++c) z[c] = sbl[c];
    for (int jq = 0; jq < 13; ++jq) {
        float t0 = sb3[jq * 4 + 0], t1 = sb3[jq * 4 + 1];
        float t2 = sb3[jq * 4 + 2], t3 = sb3[jq * 4 + 3];
        for (int k = 0; k < HID; ++k) {
            float xk = x2[k];
            float4 wv = *(const float4*)&sW3[k][jq * 4];
            t0 = fmaf(xk, wv.x, t0);
            t1 = fmaf(xk, wv.y, t1);
            t2 = fmaf(xk, wv.z, t2);
            t3 = fmaf(xk, wv.w, t3);
        }
        t0 = fmaxf(t0, 0.f); t1 = fmaxf(t1, 0.f);
        t2 = fmaxf(t2, 0.f); t3 = fmaxf(t3, 0.f);
#pragma unroll
        for (int c = 0; c < NC; ++c) {
            z[c] = fmaf(t0, sWl[jq * 4 + 0][c], z[c]);
            z[c] = fmaf(t1, sWl[jq * 4 + 1][c], z[c]);
            z[c] = fmaf(t2, sWl[jq * 4 + 2][c], z[c]);
            z[c] = fmaf(t3, sWl[jq * 4 + 3][c], z[c]);
        }
    }
#pragma unroll
    for (int c = 0; c < NC; ++c) Z[row * NC + c] = z[c];
}

// ================= two-level bucket binning =================
// Pass 1: block-aggregated scatter into coarse buckets (node>>7).
__global__ __launch_bounds__(1024) void scatter_bucket(
    const int* __restrict__ sx, const int* __restrict__ sy,
    const float* __restrict__ rel, int* __restrict__ cursor,
    uint2* __restrict__ pool, int m, int nbuck)
{
    __shared__ int hist[1024];
    __shared__ int gb[1024];
    const int t = threadIdx.x;
    hist[t] = 0;
    __syncthreads();

    const int e0 = blockIdx.x * 8192;
    unsigned rx[16], ry[16], pr[16];
#pragma unroll
    for (int k = 0; k < 8; ++k) {
        int e = e0 + k * 1024 + t;
        if (e < m) {
            int x = sx[e], y = sy[e];
            unsigned rb = __float_as_uint(rel[e]);
            int bA = x >> 7;
            int rA = atomicAdd(&hist[bA], 1);
            rx[2 * k] = (unsigned)(x & 127) | ((unsigned)y << 8);      // side 0
            ry[2 * k] = rb;
            pr[2 * k] = ((unsigned)bA << 22) | (unsigned)rA;
            int bB = y >> 7;
            int rB = atomicAdd(&hist[bB], 1);
            rx[2 * k + 1] = (unsigned)(y & 127) | 0x80u | ((unsigned)x << 8); // side 1
            ry[2 * k + 1] = rb;
            pr[2 * k + 1] = ((unsigned)bB << 22) | (unsigned)rB;
        } else {
            pr[2 * k] = 0xFFFFFFFFu; pr[2 * k + 1] = 0xFFFFFFFFu;
        }
    }
    __syncthreads();
    for (int b = t; b < nbuck; b += 1024) {
        int h = hist[b];
        gb[b] = h ? atomicAdd(&cursor[b], h) : 0;
    }
    __syncthreads();
#pragma unroll
    for (int k = 0; k < 16; ++k) {
        if (pr[k] == 0xFFFFFFFFu) continue;
        unsigned buck = pr[k] >> 22;
        unsigned rank = pr[k] & 0x3FFFFFu;
        unsigned slot = (unsigned)gb[buck] + rank;
        if (slot < BCAP)
            pool[(size_t)buck * BCAP + slot] = make_uint2(rx[k], ry[k]);
    }
}

// exclusive scan of clamped bucket counts (nb <= 1024)
__global__ __launch_bounds__(1024) void scan_buckets(
    const int* __restrict__ cursor, int* __restrict__ bucket_base, int nb)
{
    __shared__ int s[1024];
    int t = threadIdx.x;
    int v = 0;
    if (t < nb) { v = cursor[t]; if (v > BCAP) v = BCAP; }
    s[t] = v;
    __syncthreads();
    for (int st = 1; st < 1024; st <<= 1) {
        int tmp = (t >= st) ? s[t - st] : 0;
        __syncthreads();
        s[t] += tmp;
        __syncthreads();
    }
    if (t < nb) bucket_base[t] = s[t] - v;
}

// Pass 2: per-bucket LDS counting sort -> node CSR.
// Permutation built in LDS (ord[]); recs written fully COALESCED,
// gather-reads from the L2-hot 80KB pool window.
__global__ __launch_bounds__(256) void sort_bucket(
    const uint2* __restrict__ pool, const int* __restrict__ cursor,
    const int* __restrict__ bucket_base, uint2* __restrict__ recs,
    int* __restrict__ offs, int* __restrict__ deg, int n)
{
    __shared__ int hist[128], nbase[128], cur[128];
    __shared__ int sc[128];
    __shared__ ushort ord[BCAP];          // 20 KB
    const int b = blockIdx.x;
    const int t = threadIdx.x;
    int cnt = cursor[b]; if (cnt > BCAP) cnt = BCAP;
    const int base = bucket_base[b];
    if (t < 128) hist[t] = 0;
    __syncthreads();
    const uint2* bp = pool + (size_t)b * BCAP;
    for (int i = t; i < cnt; i += 256)
        atomicAdd(&hist[bp[i].x & 127u], 1);
    __syncthreads();
    int v = (t < 128) ? hist[t] : 0;
    if (t < 128) sc[t] = v;
    __syncthreads();
    for (int st = 1; st < 128; st <<= 1) {
        int tmp = (t >= st && t < 128) ? sc[t - st] : 0;
        __syncthreads();
        if (t < 128) sc[t] += tmp;
        __syncthreads();
    }
    if (t < 128) {
        nbase[t] = sc[t] - v;
        cur[t] = 0;
        int gnode = b * 128 + t;
        if (gnode < n) { offs[gnode] = base + sc[t] - v; deg[gnode] = v; }
    }
    __syncthreads();
    // build permutation in LDS
    for (int i = t; i < cnt; i += 256) {
        unsigned nl = bp[i].x & 127u;
        int rk = atomicAdd(&cur[nl], 1);
        ord[nbase[nl] + rk] = (ushort)i;
    }
    __syncthreads();
    // coalesced emit
    for (int i = t; i < cnt; i += 256) {
        uint2 r = bp[ord[i]];
        unsigned side = (r.x >> 7) & 1u;
        unsigned other = r.x >> 8;
        recs[base + i] = make_uint2(other | (side << 31), r.y);
    }
}

// ============ KENN layer as pure gather (no atomics) ============
__global__ __launch_bounds__(256) void kenn_gather(
    const float* __restrict__ Zin, float* __restrict__ Zout,
    const int* __restrict__ offs, const int* __restrict__ deg,
    const uint2* __restrict__ recs, const float* __restrict__ cw,
    int n, int dofinal)
{
    int node = blockIdx.x * 256 + threadIdx.x;
    if (node >= n) return;

    float zown[NC], acc[NC], cwv[NC];
    const float2* pz = (const float2*)(Zin + 6L * node);
#pragma unroll
    for (int q = 0; q < 3; ++q) {
        float2 t = pz[q];
        zown[2 * q] = t.x; zown[2 * q + 1] = t.y;
    }
#pragma unroll
    for (int c = 0; c < NC; ++c) { acc[c] = zown[c]; cwv[c] = cw[c]; }

    const int start = offs[node];
    const int cnt = deg[node];

#pragma unroll 2
    for (int i = 0; i < cnt; ++i) {
        uint2 rc = recs[start + i];
        const int other = (int)(rc.x & 0x7FFFFFFFu);
        const bool sideY = (rc.x & 0x80000000u) != 0;
        const float l0 = -__uint_as_float(rc.y);

        float zo[NC];
        const float2* po = (const float2*)(Zin + 6L * other);
#pragma unroll
        for (int q = 0; q < 3; ++q) {
            float2 t = po[q];
            zo[2 * q] = t.x; zo[2 * q + 1] = t.y;
        }

#pragma unroll
        for (int c = 0; c < NC; ++c) {
            float zx = sideY ? zo[c] : zown[c];
            float zy = sideY ? zown[c] : zo[c];
            float l1 = -zx;
            float l2 = zy;
            float mx = fmaxf(l0, fmaxf(l1, l2));
            float e0 = __expf(l0 - mx);
            float e1 = __expf(l1 - mx);
            float e2 = __expf(l2 - mx);
            float g = cwv[c] * __builtin_amdgcn_rcpf(e0 + e1 + e2);
            acc[c] += sideY ? (e2 * g) : (-e1 * g);
        }
    }

    if (dofinal) {
        float mx = acc[0];
#pragma unroll
        for (int c = 1; c < NC; ++c) mx = fmaxf(mx, acc[c]);
        float e[NC], s = 0.f;
#pragma unroll
        for (int c = 0; c < NC; ++c) { e[c] = __expf(acc[c] - mx); s += e[c]; }
        float inv = 1.f / s;
        float2* po = (float2*)(Zout + 6L * node);
#pragma unroll
        for (int q = 0; q < 3; ++q) {
            float2 t; t.x = e[2 * q] * inv; t.y = e[2 * q + 1] * inv;
            po[q] = t;
        }
    } else {
        float2* po = (float2*)(Zout + 6L * node);
#pragma unroll
        for (int q = 0; q < 3; ++q) {
            float2 t; t.x = acc[2 * q]; t.y = acc[2 * q + 1];
            po[q] = t;
        }
    }
}

// ---------------- fallback path kernels (atomic version) ----------------
__global__ __launch_bounds__(256) void kenn_edge(
    const float* __restrict__ Zold, float* __restrict__ Znew,
    const float* __restrict__ rel, const int* __restrict__ sx,
    const int* __restrict__ sy, const float* __restrict__ cw, int m)
{
    int idx = blockIdx.x * 256 + threadIdx.x;
    if (idx >= m) return;
    const int x = sx[idx];
    const int y = sy[idx];
    const float l0 = -rel[idx];

    float zx[NC], zy[NC];
    const float2* px = (const float2*)(Zold + 6L * x);
    const float2* py = (const float2*)(Zold + 6L * y);
#pragma unroll
    for (int q = 0; q < 3; ++q) {
        float2 t = px[q]; zx[2 * q] = t.x; zx[2 * q + 1] = t.y;
        float2 u = py[q]; zy[2 * q] = u.x; zy[2 * q + 1] = u.y;
    }
#pragma unroll
    for (int c = 0; c < NC; ++c) {
        float l1 = -zx[c];
        float l2 = zy[c];
        float mx = fmaxf(l0, fmaxf(l1, l2));
        float e0 = __expf(l0 - mx);
        float e1 = __expf(l1 - mx);
        float e2 = __expf(l2 - mx);
        float s = cw[c] / (e0 + e1 + e2);
        atomicAdd(&Znew[6L * x + c], -e1 * s);
        atomicAdd(&Znew[6L * y + c],  e2 * s);
    }
}

__global__ __launch_bounds__(256) void softmax6(
    const float* __restrict__ Z, float* __restrict__ out, int n)
{
    long row = (long)blockIdx.x * 256 + threadIdx.x;
    if (row >= n) return;
    float v[NC];
    const float2* p = (const float2*)(Z + row * 6);
#pragma unroll
    for (int q = 0; q < 3; ++q) { float2 t = p[q]; v[2 * q] = t.x; v[2 * q + 1] = t.y; }
    float mx = v[0];
#pragma unroll
    for (int c = 1; c < NC; ++c) mx = fmaxf(mx, v[c]);
    float e[NC], s = 0.f;
#pragma unroll
    for (int c = 0; c < NC; ++c) { e[c] = __expf(v[c] - mx); s += e[c]; }
    float inv = 1.f / s;
    float2* po = (float2*)(out + row * 6);
#pragma unroll
    for (int q = 0; q < 3; ++q) {
        float2 t; t.x = e[2 * q] * inv; t.y = e[2 * q + 1] * inv;
        po[q] = t;
    }
}

extern "C" void kernel_launch(void* const* d_in, const int* in_sizes, int n_in,
                              void* d_out, int out_size, void* d_ws, size_t ws_size,
                              hipStream_t stream)
{
    const float* F   = (const float*)d_in[0];
    const float* rel = (const float*)d_in[1];
    const int*   sx  = (const int*)d_in[2];
    const int*   sy  = (const int*)d_in[3];
    const float* W1  = (const float*)d_in[4];
    const float* b1  = (const float*)d_in[5];
    const float* W2  = (const float*)d_in[6];
    const float* b2  = (const float*)d_in[7];
    const float* W3  = (const float*)d_in[8];
    const float* b3  = (const float*)d_in[9];
    const float* Wl  = (const float*)d_in[10];
    const float* bl  = (const float*)d_in[11];
    const float* cw1 = (const float*)d_in[12];
    const float* cw2 = (const float*)d_in[13];
    const float* cw3 = (const float*)d_in[14];

    const int n = in_sizes[0] / D_FEAT;   // 100000
    const int m = in_sizes[1];            // 3200000
    const int nbuck = (n + 127) >> 7;     // 782

    // workspace layout (all segments 8B-aligned)
    float*  H    = (float*)d_ws;                     // n*HID
    float*  Z0   = H + (size_t)n * HID;              // n*6
    float*  Z1   = Z0 + (size_t)n * NC;              // n*6
    ushort* Whi  = (ushort*)(Z1 + (size_t)n * NC);   // 262144
    ushort* Wlo  = Whi + 262144;                     // 262144
    int* deg     = (int*)(Wlo + 262144);             // n
    int* offs    = deg + n;                          // n
    int* bbase   = offs + n;                         // 1024
    int* cursor  = bbase + 1024;                     // 1024 (nbuck used)
    uint2* recs  = (uint2*)(cursor + 1024);          // 2m
    uint2* pool  = recs + 2 * (size_t)m;             // nbuck*BCAP

    const size_t need = ((char*)(pool + (size_t)nbuck * BCAP)) - (char*)d_ws;

    prep_wfrag<<<1024, 256, 0, stream>>>(W1, Whi, Wlo);
    gemm1_mfma<<<(n + 127) / 128, 256, 0, stream>>>(F, Whi, Wlo, b1, H, n);
    mlp_tail<<<(n + 255) / 256, 256, 0, stream>>>(H, W2, b2, W3, b3, Wl, bl, Z0, n);

    const int nblk = (n + 255) / 256;
    const int eblk = (m + 255) / 256;

    if (ws_size >= need && nbuck <= 1024) {
        hipMemsetAsync(cursor, 0, (size_t)nbuck * sizeof(int), stream);
        scatter_bucket<<<(m + 8191) / 8192, 1024, 0, stream>>>(sx, sy, rel, cursor, pool, m, nbuck);
        scan_buckets<<<1, 1024, 0, stream>>>(cursor, bbase, nbuck);
        sort_bucket<<<nbuck, 256, 0, stream>>>(pool, cursor, bbase, recs, offs, deg, n);

        kenn_gather<<<nblk, 256, 0, stream>>>(Z0, Z1, offs, deg, recs, cw1, n, 0);
        kenn_gather<<<nblk, 256, 0, stream>>>(Z1, Z0, offs, deg, recs, cw2, n, 0);
        kenn_gather<<<nblk, 256, 0, stream>>>(Z0, (float*)d_out, offs, deg, recs, cw3, n, 1);
    } else {
        const size_t zbytes = (size_t)n * NC * sizeof(float);
        hipMemcpyAsync(Z1, Z0, zbytes, hipMemcpyDeviceToDevice, stream);
        kenn_edge<<<eblk, 256, 0, stream>>>(Z0, Z1, rel, sx, sy, cw1, m);
        hipMemcpyAsync(Z0, Z1, zbytes, hipMemcpyDeviceToDevice, stream);
        kenn_edge<<<eblk, 256, 0, stream>>>(Z1, Z0, rel, sx, sy, cw2, m);
        hipMemcpyAsync(Z1, Z0, zbytes, hipMemcpyDeviceToDevice, stream);
        kenn_edge<<<eblk, 256, 0, stream>>>(Z0, Z1, rel, sx, sy, cw3, m);
        softmax6<<<nblk, 256, 0, stream>>>(Z1, (float*)d_out, n);
    }
}

// Round 7
// 836.244 us; speedup vs baseline: 8.6714x; 1.0902x over previous
//
#include <hip/hip_runtime.h>

#define D_FEAT 4096
#define HID 50
#define NC 6
#define BCAP 10240   // records per bucket region (avg ~8184)
#define CSTRIDE 16   // cursor padding: 1 counter per 64B cache line

typedef __attribute__((ext_vector_type(8))) short bf16x8;
typedef __attribute__((ext_vector_type(4))) float f32x4;

// ============ W1 -> bf16 hi/lo MFMA B-fragment pre-pack ============
__global__ __launch_bounds__(256) void prep_wfrag(
    const float* __restrict__ W1, ushort* __restrict__ Whi,
    ushort* __restrict__ Wlo)
{
    int idx = blockIdx.x * 256 + threadIdx.x;   // 0 .. 128*4*64*8-1
    int j  = idx & 7;
    int l  = (idx >> 3) & 63;
    int ct = (idx >> 9) & 3;
    int kc = idx >> 11;
    int k = kc * 32 + (l >> 4) * 8 + j;
    int c = ct * 16 + (l & 15);
    float v = (c < HID) ? W1[k * HID + c] : 0.f;
    unsigned b = __float_as_uint(v);
    unsigned h = (b + 0x8000u) >> 16;                 // round-half-up bf16
    float hf = __uint_as_float(h << 16);
    float lr = v - hf;
    unsigned lo = (__float_as_uint(lr) + 0x8000u) >> 16;
    Whi[idx] = (ushort)h;
    Wlo[idx] = (ushort)lo;
}

// ---- A fp32 -> bf16 hi(trunc)/lo(trunc residual), v_perm packed ----
__device__ __forceinline__ void split_a(const f32x4 a0, const f32x4 a1,
                                        bf16x8& hi, bf16x8& lo)
{
    union U4 { unsigned u[4]; bf16x8 v; } hw, lw;
#pragma unroll
    for (int p = 0; p < 4; ++p) {
        float v0 = (p < 2) ? a0[2 * p]     : a1[2 * p - 4];
        float v1 = (p < 2) ? a0[2 * p + 1] : a1[2 * p - 3];
        unsigned b0 = __float_as_uint(v0), b1 = __float_as_uint(v1);
        hw.u[p] = __builtin_amdgcn_perm(b1, b0, 0x07060302u);
        float l0f = v0 - __uint_as_float(b0 & 0xFFFF0000u);
        float l1f = v1 - __uint_as_float(b1 & 0xFFFF0000u);
        lw.u[p] = __builtin_amdgcn_perm(__float_as_uint(l1f),
                                        __float_as_uint(l0f), 0x07060302u);
    }
    hi = hw.v; lo = lw.v;
}

// ============ GEMM1 via MFMA bf16x3: H = relu(F @ W1 + b1) ============
// (unchanged from round 6 — isolating this round's gather change)
__global__ __launch_bounds__(256, 4) void gemm1_mfma(
    const float* __restrict__ F, const ushort* __restrict__ Whi,
    const ushort* __restrict__ Wlo, const float* __restrict__ b1,
    float* __restrict__ H, int nrows)
{
    const int tid = threadIdx.x;
    const int w  = tid >> 6;
    const int l  = tid & 63;
    const int l16 = l & 15, lq = l >> 4;
    const long rowb = (long)blockIdx.x * 128 + (long)w * 32;

    const float* fp[2];
#pragma unroll
    for (int rt = 0; rt < 2; ++rt) {
        long r = rowb + rt * 16 + l16;
        if (r > (long)nrows - 1) r = (long)nrows - 1;
        fp[rt] = F + r * (long)D_FEAT + lq * 8;
    }
    const bf16x8* bhip = (const bf16x8*)Whi + l;   // + kc*256 + ct*64
    const bf16x8* blop = (const bf16x8*)Wlo + l;

    f32x4 acc[2][4];
#pragma unroll
    for (int rt = 0; rt < 2; ++rt)
#pragma unroll
        for (int ct = 0; ct < 4; ++ct)
#pragma unroll
            for (int i = 0; i < 4; ++i) acc[rt][ct][i] = 0.f;

#pragma unroll 2
    for (int kc = 0; kc < 128; ++kc) {
        f32x4 a[2][2];
#pragma unroll
        for (int rt = 0; rt < 2; ++rt) {
            a[rt][0] = *(const f32x4*)(fp[rt] + kc * 32);
            a[rt][1] = *(const f32x4*)(fp[rt] + kc * 32 + 4);
        }
        bf16x8 bh[4], bl[4];
#pragma unroll
        for (int ct = 0; ct < 4; ++ct) {
            bh[ct] = bhip[kc * 256 + ct * 64];
            bl[ct] = blop[kc * 256 + ct * 64];
        }
        bf16x8 ahi[2], alo[2];
        split_a(a[0][0], a[0][1], ahi[0], alo[0]);
        split_a(a[1][0], a[1][1], ahi[1], alo[1]);
#pragma unroll
        for (int rt = 0; rt < 2; ++rt)
#pragma unroll
            for (int ct = 0; ct < 4; ++ct) {
                acc[rt][ct] = __builtin_amdgcn_mfma_f32_16x16x32_bf16(ahi[rt], bh[ct], acc[rt][ct], 0, 0, 0);
                acc[rt][ct] = __builtin_amdgcn_mfma_f32_16x16x32_bf16(ahi[rt], bl[ct], acc[rt][ct], 0, 0, 0);
                acc[rt][ct] = __builtin_amdgcn_mfma_f32_16x16x32_bf16(alo[rt], bh[ct], acc[rt][ct], 0, 0, 0);
            }
    }

#pragma unroll
    for (int ct = 0; ct < 4; ++ct) {
        int col = ct * 16 + l16;
        if (col >= HID) continue;
        float bias = b1[col];
#pragma unroll
        for (int rt = 0; rt < 2; ++rt)
#pragma unroll
            for (int i = 0; i < 4; ++i) {
                long row = rowb + rt * 16 + lq * 4 + i;
                if (row < nrows) {
                    float v = acc[rt][ct][i] + bias;
                    H[row * HID + col] = v > 0.f ? v : 0.f;
                }
            }
    }
}

// ---------------- MLP tail ----------------
__global__ __launch_bounds__(256) void mlp_tail(
    const float* __restrict__ H,
    const float* __restrict__ W2, const float* __restrict__ b2,
    const float* __restrict__ W3, const float* __restrict__ b3,
    const float* __restrict__ Wl, const float* __restrict__ bl,
    float* __restrict__ Z, int n)
{
    __shared__ float sW2[HID][52];
    __shared__ float sW3[HID][52];
    __shared__ float sWl[52][8];
    __shared__ float sb2[52], sb3[52], sbl[8];

    for (int i = threadIdx.x; i < HID * 52; i += 256) {
        int r = i / 52, c = i % 52;
        sW2[r][c] = (c < HID) ? W2[r * HID + c] : 0.f;
        sW3[r][c] = (c < HID) ? W3[r * HID + c] : 0.f;
    }
    for (int i = threadIdx.x; i < 52 * 8; i += 256) {
        int r = i / 8, c = i % 8;
        sWl[r][c] = (r < HID && c < NC) ? Wl[r * NC + c] : 0.f;
    }
    if (threadIdx.x < 52) {
        sb2[threadIdx.x] = (threadIdx.x < HID) ? b2[threadIdx.x] : 0.f;
        sb3[threadIdx.x] = (threadIdx.x < HID) ? b3[threadIdx.x] : 0.f;
    }
    if (threadIdx.x < 8) sbl[threadIdx.x] = (threadIdx.x < NC) ? bl[threadIdx.x] : 0.f;
    __syncthreads();

    long row = (long)blockIdx.x * 256 + threadIdx.x;
    if (row >= n) return;

    float x1[HID];
#pragma unroll
    for (int i = 0; i < HID / 2; ++i) {
        float2 t = *(const float2*)(H + row * HID + 2 * i);
        x1[2 * i] = t.x; x1[2 * i + 1] = t.y;
    }

    float x2[52];
#pragma unroll
    for (int j = 0; j < 52; ++j) x2[j] = sb2[j];
    for (int i = 0; i < HID; ++i) {
        float xi = x1[i];
#pragma unroll
        for (int jq = 0; jq < 13; ++jq) {
            float4 t = *(const float4*)&sW2[i][jq * 4];
            x2[jq * 4 + 0] = fmaf(xi, t.x, x2[jq * 4 + 0]);
            x2[jq * 4 + 1] = fmaf(xi, t.y, x2[jq * 4 + 1]);
            x2[jq * 4 + 2] = fmaf(xi, t.z, x2[jq * 4 + 2]);
            x2[jq * 4 + 3] = fmaf(xi, t.w, x2[jq * 4 + 3]);
        }
    }
#pragma unroll
    for (int j = 0; j < 52; ++j) x2[j] = fmaxf(x2[j], 0.f);

    float z[NC];
#pragma unroll
    for (int c = 0; c < NC; ++c) z[c] = sbl[c];
    for (int jq = 0; jq < 13; ++jq) {
        float t0 = sb3[jq * 4 + 0], t1 = sb3[jq * 4 + 1];
        float t2 = sb3[jq * 4 + 2], t3 = sb3[jq * 4 + 3];
        for (int k = 0; k < HID; ++k) {
            float xk = x2[k];
            float4 wv = *(const float4*)&sW3[k][jq * 4];
            t0 = fmaf(xk, wv.x, t0);
            t1 = fmaf(xk, wv.y, t1);
            t2 = fmaf(xk, wv.z, t2);
            t3 = fmaf(xk, wv.w, t3);
        }
        t0 = fmaxf(t0, 0.f); t1 = fmaxf(t1, 0.f);
        t2 = fmaxf(t2, 0.f); t3 = fmaxf(t3, 0.f);
#pragma unroll
        for (int c = 0; c < NC; ++c) {
            z[c] = fmaf(t0, sWl[jq * 4 + 0][c], z[c]);
            z[c] = fmaf(t1, sWl[jq * 4 + 1][c], z[c]);
            z[c] = fmaf(t2, sWl[jq * 4 + 2][c], z[c]);
            z[c] = fmaf(t3, sWl[jq * 4 + 3][c], z[c]);
        }
    }
#pragma unroll
    for (int c = 0; c < NC; ++c) Z[row * NC + c] = z[c];
}

// ================= two-level bucket binning =================
// Pass 1: block-aggregated scatter into coarse buckets (node>>7).
// cursor is padded: 1 counter per 64B line (CSTRIDE) to kill false sharing.
__global__ __launch_bounds__(1024) void scatter_bucket(
    const int* __restrict__ sx, const int* __restrict__ sy,
    const float* __restrict__ rel, int* __restrict__ cursor,
    uint2* __restrict__ pool, int m, int nbuck)
{
    __shared__ int hist[1024];
    __shared__ int gb[1024];
    const int t = threadIdx.x;
    hist[t] = 0;
    __syncthreads();

    const int e0 = blockIdx.x * 8192;
    unsigned rx[16], ry[16], pr[16];
#pragma unroll
    for (int k = 0; k < 8; ++k) {
        int e = e0 + k * 1024 + t;
        if (e < m) {
            int x = sx[e], y = sy[e];
            unsigned rb = __float_as_uint(rel[e]);
            int bA = x >> 7;
            int rA = atomicAdd(&hist[bA], 1);
            rx[2 * k] = (unsigned)(x & 127) | ((unsigned)y << 8);      // side 0
            ry[2 * k] = rb;
            pr[2 * k] = ((unsigned)bA << 22) | (unsigned)rA;
            int bB = y >> 7;
            int rB = atomicAdd(&hist[bB], 1);
            rx[2 * k + 1] = (unsigned)(y & 127) | 0x80u | ((unsigned)x << 8); // side 1
            ry[2 * k + 1] = rb;
            pr[2 * k + 1] = ((unsigned)bB << 22) | (unsigned)rB;
        } else {
            pr[2 * k] = 0xFFFFFFFFu; pr[2 * k + 1] = 0xFFFFFFFFu;
        }
    }
    __syncthreads();
    for (int b = t; b < nbuck; b += 1024) {
        int h = hist[b];
        gb[b] = h ? atomicAdd(&cursor[b * CSTRIDE], h) : 0;
    }
    __syncthreads();
#pragma unroll
    for (int k = 0; k < 16; ++k) {
        if (pr[k] == 0xFFFFFFFFu) continue;
        unsigned buck = pr[k] >> 22;
        unsigned rank = pr[k] & 0x3FFFFFu;
        unsigned slot = (unsigned)gb[buck] + rank;
        if (slot < BCAP)
            pool[(size_t)buck * BCAP + slot] = make_uint2(rx[k], ry[k]);
    }
}

// exclusive scan of clamped bucket counts (nb <= 1024)
__global__ __launch_bounds__(1024) void scan_buckets(
    const int* __restrict__ cursor, int* __restrict__ bucket_base, int nb)
{
    __shared__ int s[1024];
    int t = threadIdx.x;
    int v = 0;
    if (t < nb) { v = cursor[t * CSTRIDE]; if (v > BCAP) v = BCAP; }
    s[t] = v;
    __syncthreads();
    for (int st = 1; st < 1024; st <<= 1) {
        int tmp = (t >= st) ? s[t - st] : 0;
        __syncthreads();
        s[t] += tmp;
        __syncthreads();
    }
    if (t < nb) bucket_base[t] = s[t] - v;
}

// Pass 2: per-bucket LDS counting sort -> node CSR, coalesced emit.
__global__ __launch_bounds__(256) void sort_bucket(
    const uint2* __restrict__ pool, const int* __restrict__ cursor,
    const int* __restrict__ bucket_base, uint2* __restrict__ recs,
    int* __restrict__ offs, int* __restrict__ deg, int n)
{
    __shared__ int hist[128], nbase[128], cur[128];
    __shared__ int sc[128];
    __shared__ ushort ord[BCAP];          // 20 KB
    const int b = blockIdx.x;
    const int t = threadIdx.x;
    int cnt = cursor[b * CSTRIDE]; if (cnt > BCAP) cnt = BCAP;
    const int base = bucket_base[b];
    if (t < 128) hist[t] = 0;
    __syncthreads();
    const uint2* bp = pool + (size_t)b * BCAP;
    for (int i = t; i < cnt; i += 256)
        atomicAdd(&hist[bp[i].x & 127u], 1);
    __syncthreads();
    int v = (t < 128) ? hist[t] : 0;
    if (t < 128) sc[t] = v;
    __syncthreads();
    for (int st = 1; st < 128; st <<= 1) {
        int tmp = (t >= st && t < 128) ? sc[t - st] : 0;
        __syncthreads();
        if (t < 128) sc[t] += tmp;
        __syncthreads();
    }
    if (t < 128) {
        nbase[t] = sc[t] - v;
        cur[t] = 0;
        int gnode = b * 128 + t;
        if (gnode < n) { offs[gnode] = base + sc[t] - v; deg[gnode] = v; }
    }
    __syncthreads();
    for (int i = t; i < cnt; i += 256) {
        unsigned nl = bp[i].x & 127u;
        int rk = atomicAdd(&cur[nl], 1);
        ord[nbase[nl] + rk] = (ushort)i;
    }
    __syncthreads();
    for (int i = t; i < cnt; i += 256) {
        uint2 r = bp[ord[i]];
        unsigned side = (r.x >> 7) & 1u;
        unsigned other = r.x >> 8;
        recs[base + i] = make_uint2(other | (side << 31), r.y);
    }
}

// ============ KENN layer: 4 threads per node, shfl reduce ============
__global__ __launch_bounds__(256) void kenn_gather4(
    const float* __restrict__ Zin, float* __restrict__ Zout,
    const int* __restrict__ offs, const int* __restrict__ deg,
    const uint2* __restrict__ recs, const float* __restrict__ cw,
    int n, int dofinal)
{
    int gt = blockIdx.x * 256 + threadIdx.x;
    int node = gt >> 2;
    int l4 = gt & 3;
    if (node >= n) return;

    float zown[NC], acc[NC], cwv[NC];
    const float2* pz = (const float2*)(Zin + 6L * node);
#pragma unroll
    for (int q = 0; q < 3; ++q) {
        float2 t = pz[q];
        zown[2 * q] = t.x; zown[2 * q + 1] = t.y;
    }
#pragma unroll
    for (int c = 0; c < NC; ++c) { acc[c] = 0.f; cwv[c] = cw[c]; }

    const int start = offs[node];
    const int cnt = deg[node];

#pragma unroll 2
    for (int i = l4; i < cnt; i += 4) {
        uint2 rc = recs[start + i];
        const int other = (int)(rc.x & 0x7FFFFFFFu);
        const bool sideY = (rc.x & 0x80000000u) != 0;
        const float l0 = -__uint_as_float(rc.y);

        float zo[NC];
        const float2* po = (const float2*)(Zin + 6L * other);
#pragma unroll
        for (int q = 0; q < 3; ++q) {
            float2 t = po[q];
            zo[2 * q] = t.x; zo[2 * q + 1] = t.y;
        }

#pragma unroll
        for (int c = 0; c < NC; ++c) {
            float zx = sideY ? zo[c] : zown[c];
            float zy = sideY ? zown[c] : zo[c];
            float l1 = -zx;
            float l2 = zy;
            float mx = fmaxf(l0, fmaxf(l1, l2));
            float e0 = __expf(l0 - mx);
            float e1 = __expf(l1 - mx);
            float e2 = __expf(l2 - mx);
            float g = cwv[c] * __builtin_amdgcn_rcpf(e0 + e1 + e2);
            acc[c] += sideY ? (e2 * g) : (-e1 * g);
        }
    }

    // reduce partial deltas across the 4 lanes of this node
#pragma unroll
    for (int c = 0; c < NC; ++c) {
        acc[c] += __shfl_xor(acc[c], 1, 64);
        acc[c] += __shfl_xor(acc[c], 2, 64);
    }

    if (l4 != 0) return;

#pragma unroll
    for (int c = 0; c < NC; ++c) acc[c] += zown[c];

    if (dofinal) {
        float mx = acc[0];
#pragma unroll
        for (int c = 1; c < NC; ++c) mx = fmaxf(mx, acc[c]);
        float e[NC], s = 0.f;
#pragma unroll
        for (int c = 0; c < NC; ++c) { e[c] = __expf(acc[c] - mx); s += e[c]; }
        float inv = 1.f / s;
        float2* po = (float2*)(Zout + 6L * node);
#pragma unroll
        for (int q = 0; q < 3; ++q) {
            float2 t; t.x = e[2 * q] * inv; t.y = e[2 * q + 1] * inv;
            po[q] = t;
        }
    } else {
        float2* po = (float2*)(Zout + 6L * node);
#pragma unroll
        for (int q = 0; q < 3; ++q) {
            float2 t; t.x = acc[2 * q]; t.y = acc[2 * q + 1];
            po[q] = t;
        }
    }
}

// ---------------- fallback path kernels (atomic version) ----------------
__global__ __launch_bounds__(256) void kenn_edge(
    const float* __restrict__ Zold, float* __restrict__ Znew,
    const float* __restrict__ rel, const int* __restrict__ sx,
    const int* __restrict__ sy, const float* __restrict__ cw, int m)
{
    int idx = blockIdx.x * 256 + threadIdx.x;
    if (idx >= m) return;
    const int x = sx[idx];
    const int y = sy[idx];
    const float l0 = -rel[idx];

    float zx[NC], zy[NC];
    const float2* px = (const float2*)(Zold + 6L * x);
    const float2* py = (const float2*)(Zold + 6L * y);
#pragma unroll
    for (int q = 0; q < 3; ++q) {
        float2 t = px[q]; zx[2 * q] = t.x; zx[2 * q + 1] = t.y;
        float2 u = py[q]; zy[2 * q] = u.x; zy[2 * q + 1] = u.y;
    }
#pragma unroll
    for (int c = 0; c < NC; ++c) {
        float l1 = -zx[c];
        float l2 = zy[c];
        float mx = fmaxf(l0, fmaxf(l1, l2));
        float e0 = __expf(l0 - mx);
        float e1 = __expf(l1 - mx);
        float e2 = __expf(l2 - mx);
        float s = cw[c] / (e0 + e1 + e2);
        atomicAdd(&Znew[6L * x + c], -e1 * s);
        atomicAdd(&Znew[6L * y + c],  e2 * s);
    }
}

__global__ __launch_bounds__(256) void softmax6(
    const float* __restrict__ Z, float* __restrict__ out, int n)
{
    long row = (long)blockIdx.x * 256 + threadIdx.x;
    if (row >= n) return;
    float v[NC];
    const float2* p = (const float2*)(Z + row * 6);
#pragma unroll
    for (int q = 0; q < 3; ++q) { float2 t = p[q]; v[2 * q] = t.x; v[2 * q + 1] = t.y; }
    float mx = v[0];
#pragma unroll
    for (int c = 1; c < NC; ++c) mx = fmaxf(mx, v[c]);
    float e[NC], s = 0.f;
#pragma unroll
    for (int c = 0; c < NC; ++c) { e[c] = __expf(v[c] - mx); s += e[c]; }
    float inv = 1.f / s;
    float2* po = (float2*)(out + row * 6);
#pragma unroll
    for (int q = 0; q < 3; ++q) {
        float2 t; t.x = e[2 * q] * inv; t.y = e[2 * q + 1] * inv;
        po[q] = t;
    }
}

extern "C" void kernel_launch(void* const* d_in, const int* in_sizes, int n_in,
                              void* d_out, int out_size, void* d_ws, size_t ws_size,
                              hipStream_t stream)
{
    const float* F   = (const float*)d_in[0];
    const float* rel = (const float*)d_in[1];
    const int*   sx  = (const int*)d_in[2];
    const int*   sy  = (const int*)d_in[3];
    const float* W1  = (const float*)d_in[4];
    const float* b1  = (const float*)d_in[5];
    const float* W2  = (const float*)d_in[6];
    const float* b2  = (const float*)d_in[7];
    const float* W3  = (const float*)d_in[8];
    const float* b3  = (const float*)d_in[9];
    const float* Wl  = (const float*)d_in[10];
    const float* bl  = (const float*)d_in[11];
    const float* cw1 = (const float*)d_in[12];
    const float* cw2 = (const float*)d_in[13];
    const float* cw3 = (const float*)d_in[14];

    const int n = in_sizes[0] / D_FEAT;   // 100000
    const int m = in_sizes[1];            // 3200000
    const int nbuck = (n + 127) >> 7;     // 782

    // workspace layout (all segments 8B-aligned)
    float*  H    = (float*)d_ws;                     // n*HID
    float*  Z0   = H + (size_t)n * HID;              // n*6
    float*  Z1   = Z0 + (size_t)n * NC;              // n*6
    ushort* Whi  = (ushort*)(Z1 + (size_t)n * NC);   // 262144
    ushort* Wlo  = Whi + 262144;                     // 262144
    int* deg     = (int*)(Wlo + 262144);             // n
    int* offs    = deg + n;                          // n
    int* bbase   = offs + n;                         // 1024
    int* cursor  = bbase + 1024;                     // 1024*CSTRIDE (nbuck used)
    uint2* recs  = (uint2*)(cursor + 1024 * CSTRIDE); // 2m
    uint2* pool  = recs + 2 * (size_t)m;             // nbuck*BCAP

    const size_t need = ((char*)(pool + (size_t)nbuck * BCAP)) - (char*)d_ws;

    prep_wfrag<<<1024, 256, 0, stream>>>(W1, Whi, Wlo);
    gemm1_mfma<<<(n + 127) / 128, 256, 0, stream>>>(F, Whi, Wlo, b1, H, n);
    mlp_tail<<<(n + 255) / 256, 256, 0, stream>>>(H, W2, b2, W3, b3, Wl, bl, Z0, n);

    const int nblk = (n + 255) / 256;
    const int g4blk = (4 * n + 255) / 256;
    const int eblk = (m + 255) / 256;

    if (ws_size >= need && nbuck <= 1024) {
        hipMemsetAsync(cursor, 0, (size_t)nbuck * CSTRIDE * sizeof(int), stream);
        scatter_bucket<<<(m + 8191) / 8192, 1024, 0, stream>>>(sx, sy, rel, cursor, pool, m, nbuck);
        scan_buckets<<<1, 1024, 0, stream>>>(cursor, bbase, nbuck);
        sort_bucket<<<nbuck, 256, 0, stream>>>(pool, cursor, bbase, recs, offs, deg, n);

        kenn_gather4<<<g4blk, 256, 0, stream>>>(Z0, Z1, offs, deg, recs, cw1, n, 0);
        kenn_gather4<<<g4blk, 256, 0, stream>>>(Z1, Z0, offs, deg, recs, cw2, n, 0);
        kenn_gather4<<<g4blk, 256, 0, stream>>>(Z0, (float*)d_out, offs, deg, recs, cw3, n, 1);
    } else {
        const size_t zbytes = (size_t)n * NC * sizeof(float);
        hipMemcpyAsync(Z1, Z0, zbytes, hipMemcpyDeviceToDevice, stream);
        kenn_edge<<<eblk, 256, 0, stream>>>(Z0, Z1, rel, sx, sy, cw1, m);
        hipMemcpyAsync(Z0, Z1, zbytes, hipMemcpyDeviceToDevice, stream);
        kenn_edge<<<eblk, 256, 0, stream>>>(Z1, Z0, rel, sx, sy, cw2, m);
        hipMemcpyAsync(Z1, Z0, zbytes, hipMemcpyDeviceToDevice, stream);
        kenn_edge<<<eblk, 256, 0, stream>>>(Z0, Z1, rel, sx, sy, cw3, m);
        softmax6<<<nblk, 256, 0, stream>>>(Z1, (float*)d_out, n);
    }
}